// Round 7
// baseline (4077.614 us; speedup 1.0000x reference)
//
#include <hip/hip_runtime.h>
#include <stdint.h>

typedef unsigned short u16;
typedef __bf16 bf16x8 __attribute__((ext_vector_type(8)));
typedef float f32x4 __attribute__((ext_vector_type(4)));

constexpr int NB = 16384;        // batch tokens
constexpr int DM = 512;          // model dim
constexpr int NS = 4;            // streams
constexpr int FH = 2048;         // FFN hidden
constexpr int XW = NS * DM;      // 2048 concat width
constexpr float EPSL = 1e-5f;

__device__ __forceinline__ float bf2f(u16 u) { return __uint_as_float(((uint32_t)u) << 16); }
__device__ __forceinline__ u16 f2bf(float f) {
  uint32_t u = __float_as_uint(f);
  u += 0x7fffu + ((u >> 16) & 1u);
  return (u16)(u >> 16);
}
__device__ __forceinline__ void unpack8(uint4 p, float* f) {
  f[0] = __uint_as_float(p.x << 16); f[1] = __uint_as_float(p.x & 0xffff0000u);
  f[2] = __uint_as_float(p.y << 16); f[3] = __uint_as_float(p.y & 0xffff0000u);
  f[4] = __uint_as_float(p.z << 16); f[5] = __uint_as_float(p.z & 0xffff0000u);
  f[6] = __uint_as_float(p.w << 16); f[7] = __uint_as_float(p.w & 0xffff0000u);
}
__device__ __forceinline__ uint4 pack8(const float* f) {
  uint4 r;
  r.x = (uint32_t)f2bf(f[0]) | ((uint32_t)f2bf(f[1]) << 16);
  r.y = (uint32_t)f2bf(f[2]) | ((uint32_t)f2bf(f[3]) << 16);
  r.z = (uint32_t)f2bf(f[4]) | ((uint32_t)f2bf(f[5]) << 16);
  r.w = (uint32_t)f2bf(f[6]) | ((uint32_t)f2bf(f[7]) << 16);
  return r;
}
__device__ __forceinline__ void gl_lds16(const void* g, void* l) {
  __builtin_amdgcn_global_load_lds((const __attribute__((address_space(1))) void*)g,
                                   (__attribute__((address_space(3))) void*)l, 16, 0, 0);
}

// XCD-aware bijective remap. gx%8==0 required (all launches satisfy).
__device__ __forceinline__ void remap(int& bx, int& by, int& bz) {
  const int gx = gridDim.x, gy = gridDim.y;
  const int fl = (blockIdx.z * gy + blockIdx.y) * gx + blockIdx.x;
  const int xcd = fl & 7;
  const int t = fl >> 3;
  const int bw = gx >> 3;
  bx = xcd * bw + t % bw;
  const int u = t / bw;
  by = u % gy;
  bz = u / gy;
}

// ---- chained 128x128 GEMM core: 3-buffer counted-vmcnt pipeline (r5 ledger),
// NSEG segments run back-to-back through ONE pipeline (virtual step v; buffer
// v%3; stage v+2; steady wait vmcnt(4)). Per-seg A/B base shift segA/segB
// (elements). After each segment's last MFMA, epi(seg, acc) runs, then acc=0.
// Epi vmem only inflates outstanding count -> subsequent vmcnt(4) OVER-waits
// (safe). Swizzle: global source 16B-block ^= key, reads apply same XOR.
template<int NSEG, class Epi>
__device__ __forceinline__ void gemm_chain(
    const u16* __restrict__ A, long segA, int lda,
    const u16* __restrict__ Bt, long segB, int K, int ntl,
    u16* As, u16* Bs, int m0, int n0, Epi epi)
{
  const int tid = threadIdx.x;
  const int ln = tid & 63;
  const int w  = tid >> 6;
  const int wm = w >> 1, wn = w & 1;
  const int grow = ln >> 2;
  const int gcol = ((ln & 3) ^ ((ln >> 3) & 3)) * 8;   // swizzled src 16B-block
  const u16* Ab = A  + (size_t)(m0 + w * 32 + grow) * lda + gcol;
  const u16* Bb = Bt + (size_t)(n0 + w * 32 + grow) * K   + gcol;
  const int nt = K >> 5, NT = nt * NSEG, ntm = nt - 1;

  auto stage = [&](int buf, int v) {
    const int seg = v >> ntl;
    const int k0 = (v & ntm) << 5;
    const u16* a = Ab + (long)seg * segA + k0;
    const u16* b = Bb + (long)seg * segB + k0;
#pragma unroll
    for (int i = 0; i < 2; ++i) {
      gl_lds16(a + (size_t)(i * 16) * lda, &As[buf * 4096 + (w * 32 + i * 16) * 32]);
      gl_lds16(b + (size_t)(i * 16) * K,   &Bs[buf * 4096 + (w * 32 + i * 16) * 32]);
    }
  };

  f32x4 acc[4][4] = {};
  stage(0, 0);
  stage(1, 1);
  asm volatile("s_waitcnt vmcnt(4)" ::: "memory");     // tile 0 landed
  __builtin_amdgcn_s_barrier();
  asm volatile("" ::: "memory");

  const int cb = ((ln >> 4) ^ (((ln & 15) >> 1) & 3)) * 8;  // swizzled read blk
  int cur = 0, nxt = 2;
  for (int v = 0; v < NT; ++v) {
    if (v + 2 < NT) stage(nxt, v + 2);
    bf16x8 af[4], bfv[4];
#pragma unroll
    for (int m = 0; m < 4; ++m) {
      af[m]  = *(const bf16x8*)&As[cur * 4096 + (wm * 64 + m * 16 + (ln & 15)) * 32 + cb];
      bfv[m] = *(const bf16x8*)&Bs[cur * 4096 + (wn * 64 + m * 16 + (ln & 15)) * 32 + cb];
    }
#pragma unroll
    for (int m = 0; m < 4; ++m)
#pragma unroll
      for (int n = 0; n < 4; ++n)
        acc[m][n] = __builtin_amdgcn_mfma_f32_16x16x32_bf16(af[m], bfv[n], acc[m][n], 0, 0, 0);
    if ((v & ntm) == ntm) {          // segment end: epilogue, reset acc
      epi(v >> ntl, acc);
#pragma unroll
      for (int m = 0; m < 4; ++m)
#pragma unroll
        for (int n = 0; n < 4; ++n) acc[m][n] = f32x4{0.f, 0.f, 0.f, 0.f};
    }
    if (v + 2 < NT)      asm volatile("s_waitcnt vmcnt(4)" ::: "memory");
    else if (v + 1 < NT) asm volatile("s_waitcnt vmcnt(0)" ::: "memory");
    else break;
    __builtin_amdgcn_s_barrier();
    asm volatile("" ::: "memory");
    cur = cur + 1; if (cur == 3) cur = 0;
    nxt = nxt + 1; if (nxt == 3) nxt = 0;
  }
}

// generic chained GEMM: per seg C = A_seg*B_seg^T + bias_seg [+Rsd][ReLU]
// mspan: rows per block (128 or 128*NSEG for m-chain); segM: row shift per seg.
template<bool RELU, bool RESID, bool OUTF32, int NSEG>
__global__ __launch_bounds__(256) void k_gemm(
    const u16* __restrict__ A, long segA, int lda, int mspan, int segM,
    const u16* __restrict__ Bt, long segB,
    const float* __restrict__ bias, long biasZ,
    const u16* __restrict__ Rsd, int ldr, long rZ,
    void* __restrict__ Cp, int ldc, long cZ, int K, int ntl)
{
  int bx, by, bz; remap(bx, by, bz); (void)bz;
  __shared__ alignas(16) u16 As[3 * 4096];
  __shared__ alignas(16) u16 Bs[3 * 4096];
  const int ln = threadIdx.x & 63;
  const int w = threadIdx.x >> 6;
  const int wm = w >> 1, wn = w & 1;
  const int m0 = bx * mspan, n0 = by * 128;
  auto epi = [&](int seg, f32x4 (&acc)[4][4]) {
    const float* bs = bias + (long)seg * biasZ;
#pragma unroll
    for (int n = 0; n < 4; ++n) {
      const int gc = n0 + wn * 64 + n * 16 + (ln & 15);
      const float bv = bs[gc];
#pragma unroll
      for (int m = 0; m < 4; ++m) {
#pragma unroll
        for (int j = 0; j < 4; ++j) {
          const int gr = m0 + seg * segM + wm * 64 + m * 16 + (ln >> 4) * 4 + j;
          float v = acc[m][n][j] + bv;
          if constexpr (RESID) v += bf2f(Rsd[(long)seg * rZ + (size_t)gr * ldr + gc]);
          if constexpr (RELU)  v = v > 0.f ? v : 0.f;
          if constexpr (OUTF32) ((float*)Cp)[(long)seg * cZ + (size_t)gr * ldc + gc] = v;
          else                  ((u16*)Cp)[(long)seg * cZ + (size_t)gr * ldc + gc] = f2bf(v);
        }
      }
    }
  };
  gemm_chain<NSEG>(A, segA, lda, Bt, segB, K, ntl, As, Bs, m0, n0, epi);
}

// K-projection chained over kp (seg=kp), z = s. Fused q.k dot epilogue
// writes raw scores (x1/8) to wbuf[s][b][h][kp]. K-bias softmax-invariant.
__global__ __launch_bounds__(256) void k_kdot(
    const u16* __restrict__ xcat, const u16* __restrict__ WkT_l,
    const u16* __restrict__ Qb, float* __restrict__ wbuf)
{
  int bx, by, s; remap(bx, by, s);
  __shared__ alignas(16) u16 As[3 * 4096];
  __shared__ alignas(16) u16 Bs[3 * 4096];
  const int ln = threadIdx.x & 63;
  const int w = threadIdx.x >> 6;
  const int wm = w >> 1, wn = w & 1;
  const int m0 = bx * 128, n0 = by * 128;
  const int h = (n0 >> 6) + wn;
  auto epi = [&](int kp, f32x4 (&acc)[4][4]) {
    float p[4][4];
#pragma unroll
    for (int m = 0; m < 4; ++m)
#pragma unroll
      for (int j = 0; j < 4; ++j) p[m][j] = 0.f;
#pragma unroll
    for (int n = 0; n < 4; ++n) {
      const int gc = n0 + wn * 64 + n * 16 + (ln & 15);
#pragma unroll
      for (int m = 0; m < 4; ++m) {
#pragma unroll
        for (int j = 0; j < 4; ++j) {
          const int gr = m0 + wm * 64 + m * 16 + (ln >> 4) * 4 + j;
          p[m][j] += acc[m][n][j] * bf2f(Qb[((size_t)s * NB + gr) * DM + gc]);
        }
      }
    }
#pragma unroll
    for (int m = 0; m < 4; ++m)
#pragma unroll
      for (int j = 0; j < 4; ++j) {
        float v = p[m][j];
        v += __shfl_xor(v, 1, 64);
        v += __shfl_xor(v, 2, 64);
        v += __shfl_xor(v, 4, 64);
        v += __shfl_xor(v, 8, 64);
        p[m][j] = v;
      }
    if ((ln & 15) == 0) {
#pragma unroll
      for (int m = 0; m < 4; ++m)
#pragma unroll
        for (int j = 0; j < 4; ++j) {
          const int gr = m0 + wm * 64 + m * 16 + (ln >> 4) * 4 + j;
          wbuf[(((size_t)s * NB + gr) * 8 + h) * 4 + kp] = p[m][j] * 0.125f;
        }
    }
  };
  gemm_chain<4>(xcat, DM, XW, WkT_l + (size_t)s * DM * DM, 0, DM, 4,
                As, Bs, m0, n0, epi);
}

// V-projection chained over kp (seg=kp): facc += w[s,b,h,kp]*((x_kp Wv)_gc+bv);
// single bf16 ctxc write at the end.
__global__ __launch_bounds__(256) void k_gemmv4(
    const u16* __restrict__ xcat, const u16* __restrict__ WvT_l,
    const float* __restrict__ bv_l, const float* __restrict__ wbuf,
    u16* __restrict__ ctxc)
{
  int bx, by, bz; remap(bx, by, bz); (void)bz;
  __shared__ alignas(16) u16 As[3 * 4096];
  __shared__ alignas(16) u16 Bs[3 * 4096];
  const int ln = threadIdx.x & 63;
  const int w = threadIdx.x >> 6;
  const int wm = w >> 1, wn = w & 1;
  const int m0 = bx * 128, n0 = by * 128;
  const int s  = n0 >> 9;
  const int hh = ((n0 >> 6) + wn) & 7;
  f32x4 facc[4][4] = {};
  auto epi = [&](int kp, f32x4 (&acc)[4][4]) {
    float wv[4][4];
#pragma unroll
    for (int m = 0; m < 4; ++m)
#pragma unroll
      for (int j = 0; j < 4; ++j) {
        const int gr = m0 + wm * 64 + m * 16 + (ln >> 4) * 4 + j;
        wv[m][j] = wbuf[(((size_t)s * NB + gr) * 8 + hh) * 4 + kp];
      }
#pragma unroll
    for (int n = 0; n < 4; ++n) {
      const float bvv = bv_l[n0 + wn * 64 + n * 16 + (ln & 15)];
#pragma unroll
      for (int m = 0; m < 4; ++m)
#pragma unroll
        for (int j = 0; j < 4; ++j)
          facc[m][n][j] += (acc[m][n][j] + bvv) * wv[m][j];
    }
  };
  gemm_chain<4>(xcat, DM, XW, WvT_l, 0, DM, 4, As, Bs, m0, n0, epi);
#pragma unroll
  for (int n = 0; n < 4; ++n) {
    const int gc = n0 + wn * 64 + n * 16 + (ln & 15);
#pragma unroll
    for (int m = 0; m < 4; ++m)
#pragma unroll
      for (int j = 0; j < 4; ++j) {
        const int gr = m0 + wm * 64 + m * 16 + (ln >> 4) * 4 + j;
        ctxc[(size_t)gr * XW + gc] = f2bf(facc[m][n][j]);
      }
  }
}

// softmax over kp in-place on wbuf [S][B][H][4]; optional write to attn0
__global__ __launch_bounds__(256) void k_softmax(
    float* __restrict__ wbuf, float* __restrict__ a0)
{
  const int t = blockIdx.x * 256 + threadIdx.x;   // (s*NB + b)*8 + h
  float4 v = ((const float4*)wbuf)[t];
  const float mx = fmaxf(fmaxf(v.x, v.y), fmaxf(v.z, v.w));
  float4 e;
  e.x = __expf(v.x - mx); e.y = __expf(v.y - mx);
  e.z = __expf(v.z - mx); e.w = __expf(v.w - mx);
  const float inv = 1.f / (e.x + e.y + e.z + e.w);
  e.x *= inv; e.y *= inv; e.z *= inv; e.w *= inv;
  ((float4*)wbuf)[t] = e;
  if (a0 != nullptr) {
    const int s = t >> 17, b = (t >> 3) & (NB - 1), h = t & 7;
    ((float4*)a0)[((size_t)b * NS + s) * 8 + h] = e;
  }
}

// in-place LayerNorm over each 512-wide stream block of xcat; wave per (b,s)
__global__ __launch_bounds__(256) void k_ln(
    u16* __restrict__ xcat, const float* __restrict__ g, const float* __restrict__ bb)
{
  const int ln = threadIdx.x & 63;
  const int row = blockIdx.x * 4 + (threadIdx.x >> 6);
  const int b = row >> 2, s = row & 3;
  u16* p = xcat + (size_t)b * XW + s * DM;
  float v[8];
  { uint4 t = ((const uint4*)p)[ln]; unpack8(t, v); }
  float sum = 0.f;
#pragma unroll
  for (int j = 0; j < 8; ++j) sum += v[j];
#pragma unroll
  for (int off = 1; off < 64; off <<= 1) sum += __shfl_xor(sum, off, 64);
  const float mu = sum * (1.f / DM);
  float s2 = 0.f;
#pragma unroll
  for (int j = 0; j < 8; ++j) { float d = v[j] - mu; s2 += d * d; }
#pragma unroll
  for (int off = 1; off < 64; off <<= 1) s2 += __shfl_xor(s2, off, 64);
  const float rs = rsqrtf(s2 * (1.f / DM) + EPSL);
  const int e0 = s * DM + ln * 8;
  float o[8];
#pragma unroll
  for (int j = 0; j < 8; ++j) o[j] = (v[j] - mu) * rs * g[e0 + j] + bb[e0 + j];
  ((uint4*)p)[ln] = pack8(o);
}

// pack 4 fp32 streams -> xcat bf16 [B][S*D]
__global__ void k_pack(const float* __restrict__ t0, const float* __restrict__ t1,
                       const float* __restrict__ t2, const float* __restrict__ t3,
                       u16* __restrict__ xcat)
{
  const int total = NB * XW / 8;
  for (int t = blockIdx.x * blockDim.x + threadIdx.x; t < total; t += gridDim.x * blockDim.x) {
    const int b = t >> 8;
    const int r = t & 255;
    const int s = r >> 6;
    const int d0 = (r & 63) * 8;
    const float* p = (s == 0) ? t0 : (s == 1) ? t1 : (s == 2) ? t2 : t3;
    float f[8];
#pragma unroll
    for (int j = 0; j < 8; ++j) f[j] = p[(size_t)b * DM + d0 + j];
    ((uint4*)xcat)[t] = pack8(f);
  }
}

// transpose + fp32->bf16: src nb x [R][C] -> dst nb x [C][R]; pow2 dims
__global__ void k_tcvt(const float* __restrict__ src, u16* __restrict__ dst,
                       int rlog, int clog, int nb)
{
  const int mlog = rlog + clog;
  const size_t total = (size_t)nb << mlog;
  for (size_t t = (size_t)blockIdx.x * blockDim.x + threadIdx.x; t < total;
       t += (size_t)gridDim.x * blockDim.x) {
    const size_t mat = t >> mlog;
    const uint32_t rem = (uint32_t)(t & ((1u << mlog) - 1));
    const uint32_t n = rem >> rlog;
    const uint32_t r = rem & ((1u << rlog) - 1);
    dst[t] = f2bf(src[(mat << mlog) + ((size_t)r << clog) + n]);
  }
}

extern "C" void kernel_launch(void* const* d_in, const int* in_sizes, int n_in,
                              void* d_out, int out_size, void* d_ws, size_t ws_size,
                              hipStream_t stream)
{
  (void)in_sizes; (void)n_in; (void)out_size;
  const float* t0  = (const float*)d_in[0];
  const float* t1  = (const float*)d_in[1];
  const float* t2  = (const float*)d_in[2];
  const float* t3  = (const float*)d_in[3];
  const float* Wq  = (const float*)d_in[4];
  const float* bq  = (const float*)d_in[5];
  const float* Wk  = (const float*)d_in[6];
  const float* Wv  = (const float*)d_in[8];
  const float* bv  = (const float*)d_in[9];
  const float* Wo  = (const float*)d_in[10];
  const float* bo  = (const float*)d_in[11];
  const float* lng = (const float*)d_in[12];
  const float* lnb = (const float*)d_in[13];
  const float* W1  = (const float*)d_in[14];
  const float* b1  = (const float*)d_in[15];
  const float* W2  = (const float*)d_in[16];
  const float* b2  = (const float*)d_in[17];
  const float* Wf1 = (const float*)d_in[18];
  const float* bf1 = (const float*)d_in[19];
  const float* Wf2 = (const float*)d_in[20];
  const float* bf2 = (const float*)d_in[21];

  size_t off = 0;
  char* ws = (char*)d_ws;
  auto take = [&](size_t n) { char* p = ws + off; off += (n + 255) & ~(size_t)255; return p; };
  u16* WqT  = (u16*)take(8ull * DM * DM * 2);        //  4 MiB
  u16* WkT  = (u16*)take(8ull * DM * DM * 2);        //  4
  u16* WvT  = (u16*)take(8ull * DM * DM * 2);        //  4
  u16* WoT  = (u16*)take(8ull * DM * DM * 2);        //  4
  u16* W1T  = (u16*)take(8ull * DM * FH * 2);        // 16
  u16* W2T  = (u16*)take(8ull * FH * DM * 2);        // 16
  u16* Wf1T = (u16*)take((size_t)XW * 1024 * 2);     //  4
  u16* Wf2T = (u16*)take((size_t)1024 * DM * 2);     //  1
  u16* xcat = (u16*)take((size_t)NB * XW * 2);       // 64
  char* U1  = take((size_t)NB * XW * 2);             // 64: Qb | ctxc | ffn1 | y1
  float* wbuf = (float*)take(4ull * NB * 8 * 4 * 4); //  8
  const size_t needed = off;                          // ~189 MiB

  u16* Qb   = (u16*)U1;   // [S][B][512]
  u16* ctxc = (u16*)U1;   // [B][2048]
  u16* ffn1 = (u16*)U1;   // [B][2048] per stream
  u16* y1   = (u16*)U1;   // [B][1024]
  float* attn0 = (float*)d_out + (size_t)NB * DM;

  if (needed > ws_size) return;  // diagnostic: clean fail instead of GPU fault

  // weight prep: fp32 -> bf16, transposed to [N][K]
  k_tcvt<<<dim3(1024), dim3(256), 0, stream>>>(Wq, WqT, 9, 9, 8);
  k_tcvt<<<dim3(1024), dim3(256), 0, stream>>>(Wk, WkT, 9, 9, 8);
  k_tcvt<<<dim3(1024), dim3(256), 0, stream>>>(Wv, WvT, 9, 9, 8);
  k_tcvt<<<dim3(1024), dim3(256), 0, stream>>>(Wo, WoT, 9, 9, 8);
  k_tcvt<<<dim3(1024), dim3(256), 0, stream>>>(W1, W1T, 9, 11, 8);
  k_tcvt<<<dim3(1024), dim3(256), 0, stream>>>(W2, W2T, 11, 9, 8);
  k_tcvt<<<dim3(1024), dim3(256), 0, stream>>>(Wf1, Wf1T, 11, 10, 1);
  k_tcvt<<<dim3(1024), dim3(256), 0, stream>>>(Wf2, Wf2T, 10, 9, 1);
  k_pack<<<dim3(2048), dim3(256), 0, stream>>>(t0, t1, t2, t3, xcat);

  const long WSQ = (long)DM * DM;
  for (int ly = 0; ly < 2; ++ly) {
    const u16* WqT_l = WqT + (size_t)ly * 4 * WSQ;
    const u16* WkT_l = WkT + (size_t)ly * 4 * WSQ;
    const u16* WvT_l = WvT + (size_t)ly * 4 * WSQ;
    const u16* WoT_l = WoT + (size_t)ly * 4 * WSQ;
    // Q projection: one launch, chained over streams (seg=s; A+B shift)
    k_gemm<false, false, false, 4><<<dim3(128, 4), dim3(256), 0, stream>>>(
        xcat, DM, XW, 128, 0, WqT_l, WSQ, bq + (size_t)ly * XW, DM,
        nullptr, 0, 0, Qb, DM, (long)NB * DM, DM, 4);
    // K projection + fused q.k dot: chained over kp, z = s
    k_kdot<<<dim3(128, 4, 4), dim3(256), 0, stream>>>(xcat, WkT_l, Qb, wbuf);
    k_softmax<<<dim3(4 * NB * 8 / 256), dim3(256), 0, stream>>>(
        wbuf, (ly == 0) ? attn0 : (float*)nullptr);
    // V projection: chained over kp, fp32 reg accumulate, one ctxc write
    k_gemmv4<<<dim3(128, 16), dim3(256), 0, stream>>>(
        xcat, WvT_l, bv + (size_t)ly * XW, wbuf, ctxc);
    // O projection: one launch, chained over streams, residual in-place
    k_gemm<false, true, false, 4><<<dim3(128, 4), dim3(256), 0, stream>>>(
        ctxc, DM, XW, 128, 0, WoT_l, WSQ, bo + (size_t)ly * XW, DM,
        xcat, XW, DM, xcat, XW, DM, DM, 4);
    k_ln<<<dim3(NB), dim3(256), 0, stream>>>(xcat, lng + ly * XW, lnb + ly * XW);
    // FFN per stream, residual-fused, in-place; FFN1 chained over bx rows
    for (int s = 0; s < NS; ++s) {
      const size_t wsl = (size_t)(ly * 4 + s);
      k_gemm<true, false, false, 4><<<dim3(32, 16), dim3(256), 0, stream>>>(
          xcat + s * DM, (long)128 * XW, XW, 512, 128,
          W1T + wsl * (size_t)DM * FH, 0, b1 + wsl * FH, 0,
          nullptr, 0, 0, ffn1, FH, 0, DM, 4);
      k_gemm<false, true, false, 1><<<dim3(128, 4), dim3(256), 0, stream>>>(
          ffn1, 0, FH, 128, 0, W2T + wsl * (size_t)FH * DM, 0, b2 + wsl * DM, 0,
          xcat + s * DM, XW, 0, xcat + s * DM, XW, 0, FH, 6);
    }
  }
  // final fusion MLP
  k_gemm<true, false, false, 1><<<dim3(128, 8), dim3(256), 0, stream>>>(
      xcat, 0, XW, 128, 0, Wf1T, 0, bf1, 0, nullptr, 0, 0, y1, 1024, 0, XW, 6);
  k_gemm<false, false, true, 1><<<dim3(128, 4), dim3(256), 0, stream>>>(
      y1, 0, 1024, 128, 0, Wf2T, 0, bf2, 0, nullptr, 0, 0, d_out, DM, 0, 1024, 5);
}

// Round 8
// 3482.769 us; speedup vs baseline: 1.1708x; 1.1708x over previous
//
#include <hip/hip_runtime.h>
#include <stdint.h>

typedef unsigned short u16;
typedef __bf16 bf16x8 __attribute__((ext_vector_type(8)));
typedef float f32x4 __attribute__((ext_vector_type(4)));

constexpr int NB = 16384;        // batch tokens
constexpr int DM = 512;          // model dim
constexpr int NS = 4;            // streams
constexpr int FH = 2048;         // FFN hidden
constexpr int XW = NS * DM;      // 2048 concat width
constexpr float EPSL = 1e-5f;

__device__ __forceinline__ float bf2f(u16 u) { return __uint_as_float(((uint32_t)u) << 16); }
__device__ __forceinline__ u16 f2bf(float f) {
  uint32_t u = __float_as_uint(f);
  u += 0x7fffu + ((u >> 16) & 1u);
  return (u16)(u >> 16);
}
__device__ __forceinline__ void unpack8(uint4 p, float* f) {
  f[0] = __uint_as_float(p.x << 16); f[1] = __uint_as_float(p.x & 0xffff0000u);
  f[2] = __uint_as_float(p.y << 16); f[3] = __uint_as_float(p.y & 0xffff0000u);
  f[4] = __uint_as_float(p.z << 16); f[5] = __uint_as_float(p.z & 0xffff0000u);
  f[6] = __uint_as_float(p.w << 16); f[7] = __uint_as_float(p.w & 0xffff0000u);
}
__device__ __forceinline__ uint4 pack8(const float* f) {
  uint4 r;
  r.x = (uint32_t)f2bf(f[0]) | ((uint32_t)f2bf(f[1]) << 16);
  r.y = (uint32_t)f2bf(f[2]) | ((uint32_t)f2bf(f[3]) << 16);
  r.z = (uint32_t)f2bf(f[4]) | ((uint32_t)f2bf(f[5]) << 16);
  r.w = (uint32_t)f2bf(f[6]) | ((uint32_t)f2bf(f[7]) << 16);
  return r;
}
__device__ __forceinline__ void gl_lds16(const void* g, void* l) {
  __builtin_amdgcn_global_load_lds((const __attribute__((address_space(1))) void*)g,
                                   (__attribute__((address_space(3))) void*)l, 16, 0, 0);
}

// XCD-aware bijective remap. gx%8==0 required (all launches satisfy).
__device__ __forceinline__ void remap(int& bx, int& by, int& bz) {
  const int gx = gridDim.x, gy = gridDim.y;
  const int fl = (blockIdx.z * gy + blockIdx.y) * gx + blockIdx.x;
  const int xcd = fl & 7;
  const int t = fl >> 3;
  const int bw = gx >> 3;
  bx = xcd * bw + t % bw;
  const int u = t / bw;
  by = u % gy;
  bz = u / gy;
}

// ---- 128x128 GEMM core, BK=64, 2 buffers, FRAG-MAJOR LDS ----
// Rationale (m233): barrier+stage serialization is the structural cost of the
// 2-phase loop; BK=64 halves barrier-pairs per FLOP (32 MFMA + 16 ds_read per
// barrier-pair). Frag-major LDS (proven r6): each 16-lane fragment's 64 lanes
// stored contiguously -> ds_read_b128 is a wave-contiguous 1KB burst (zero
// bank conflicts) and is global_load_lds' native wave-uniform-base dest.
// Fragment fr of chunk kk: lane ln holds elem [row fr*16+(ln&15)]
// [k = kk*32+(ln>>4)*8 ..+8]. A and B use identical k mapping (consistent).
__device__ __forceinline__ void gemm64(
    const u16* __restrict__ A, int lda,
    const u16* __restrict__ Bt, int K,    // Bt row stride == K
    u16* As, u16* Bs, f32x4 (&acc)[4][4], int bx, int by)
{
  const int tid = threadIdx.x;
  const int ln = tid & 63;
  const int w  = tid >> 6;               // 0..3
  const int wm = w >> 1, wn = w & 1;
  const int m0 = bx * 128;
  const int n0 = by * 128;
  const u16* Ab = A  + (size_t)(m0 + w * 16 + (ln & 15)) * lda + ((ln >> 4) & 3) * 8;
  const u16* Bb = Bt + (size_t)(n0 + w * 16 + (ln & 15)) * K   + ((ln >> 4) & 3) * 8;

  // stage one BK=64 tile: 8 gl_lds/wave (4 A + 4 B), dst wave-uniform + ln*16B
  auto stage = [&](int buf, int k0) {
#pragma unroll
    for (int kk = 0; kk < 2; ++kk)
#pragma unroll
      for (int i = 0; i < 2; ++i) {
        gl_lds16(Ab + (size_t)(i * 64) * lda + k0 + kk * 32,
                 &As[buf * 8192 + ((kk * 8 + i * 4 + w) * 512) + ln * 8]);
        gl_lds16(Bb + (size_t)(i * 64) * K + k0 + kk * 32,
                 &Bs[buf * 8192 + ((kk * 8 + i * 4 + w) * 512) + ln * 8]);
      }
  };

  __syncthreads();                       // protect LDS reuse across calls
  const int nt = K >> 6;
  stage(0, 0);
  asm volatile("s_waitcnt vmcnt(0)" ::: "memory");
  __builtin_amdgcn_s_barrier();
  asm volatile("" ::: "memory");

  int buf = 0;
  for (int t = 0; t < nt; ++t) {
    if (t + 1 < nt) stage(buf ^ 1, (t + 1) * 64);
    bf16x8 af[4][2], bfv[4][2];
#pragma unroll
    for (int kk = 0; kk < 2; ++kk) {
#pragma unroll
      for (int mf = 0; mf < 4; ++mf)
        af[mf][kk] = *(const bf16x8*)&As[buf * 8192 + (kk * 8 + wm * 4 + mf) * 512 + ln * 8];
#pragma unroll
      for (int nf = 0; nf < 4; ++nf)
        bfv[nf][kk] = *(const bf16x8*)&Bs[buf * 8192 + (kk * 8 + wn * 4 + nf) * 512 + ln * 8];
    }
#pragma unroll
    for (int kk = 0; kk < 2; ++kk)
#pragma unroll
      for (int mf = 0; mf < 4; ++mf)
#pragma unroll
        for (int nf = 0; nf < 4; ++nf)
          acc[mf][nf] = __builtin_amdgcn_mfma_f32_16x16x32_bf16(
              af[mf][kk], bfv[nf][kk], acc[mf][nf], 0, 0, 0);
    if (t + 1 == nt) break;
    asm volatile("s_waitcnt vmcnt(0)" ::: "memory");   // next tile landed
    __builtin_amdgcn_s_barrier();
    asm volatile("" ::: "memory");
    buf ^= 1;
  }
  asm volatile("" ::: "memory");         // fence: epilogue must not hoist
}

// generic GEMM with per-z offsets: C = A*Bt^T + bias [+Rsd][ReLU]
template<bool RELU, bool RESID, bool OUTF32>
__global__ __launch_bounds__(256) void k_gemm(
    const u16* __restrict__ A, int lda, long aZ,
    const u16* __restrict__ Bt, long bZ,
    const float* __restrict__ bias, long biasZ,
    const u16* __restrict__ Rsd, int ldr, long rZ,
    void* __restrict__ Cp, int ldc, long cZ, int K)
{
  int bx, by, bz; remap(bx, by, bz);
  A += (long)bz * aZ; Bt += (long)bz * bZ; bias += (long)bz * biasZ;
  __shared__ alignas(16) u16 As[2 * 8192];
  __shared__ alignas(16) u16 Bs[2 * 8192];
  f32x4 acc[4][4] = {};
  gemm64(A, lda, Bt, K, As, Bs, acc, bx, by);
  const int ln = threadIdx.x & 63;
  const int w = threadIdx.x >> 6;
  const int wm = w >> 1, wn = w & 1;
  const int m0 = bx * 128, n0 = by * 128;
#pragma unroll
  for (int nf = 0; nf < 4; ++nf) {
    const int gc = n0 + wn * 64 + nf * 16 + (ln & 15);
    const float bv = bias[gc];
#pragma unroll
    for (int mf = 0; mf < 4; ++mf) {
#pragma unroll
      for (int j = 0; j < 4; ++j) {
        const int gr = m0 + wm * 64 + mf * 16 + (ln >> 4) * 4 + j;
        float v = acc[mf][nf][j] + bv;
        if constexpr (RESID) v += bf2f(Rsd[(long)bz * rZ + (size_t)gr * ldr + gc]);
        if constexpr (RELU)  v = v > 0.f ? v : 0.f;
        if constexpr (OUTF32) ((float*)Cp)[(long)bz * cZ + (size_t)gr * ldc + gc] = v;
        else                  ((u16*)Cp)[(long)bz * cZ + (size_t)gr * ldc + gc] = f2bf(v);
      }
    }
  }
}

// K-projection GEMM with fused q.k dot epilogue. z = s*4+kp.
// Writes raw scores (x1/8) to wbuf[s][b][h][kp]. K-bias softmax-invariant.
__global__ __launch_bounds__(256) void k_kdot(
    const u16* __restrict__ xcat, const u16* __restrict__ WkT_l,
    const u16* __restrict__ Qb, float* __restrict__ wbuf)
{
  int bx, by, bz; remap(bx, by, bz);
  const int s = bz >> 2, kp = bz & 3;
  __shared__ alignas(16) u16 As[2 * 8192];
  __shared__ alignas(16) u16 Bs[2 * 8192];
  f32x4 acc[4][4] = {};
  gemm64(xcat + kp * DM, XW, WkT_l + (size_t)s * DM * DM, DM, As, Bs, acc, bx, by);
  const int ln = threadIdx.x & 63;
  const int w = threadIdx.x >> 6;
  const int wm = w >> 1, wn = w & 1;
  const int m0 = bx * 128, n0 = by * 128;
  const int h = (n0 >> 6) + wn;
  float p[4][4];
#pragma unroll
  for (int m = 0; m < 4; ++m)
#pragma unroll
    for (int j = 0; j < 4; ++j) p[m][j] = 0.f;
#pragma unroll
  for (int n = 0; n < 4; ++n) {
    const int gc = n0 + wn * 64 + n * 16 + (ln & 15);
#pragma unroll
    for (int m = 0; m < 4; ++m) {
#pragma unroll
      for (int j = 0; j < 4; ++j) {
        const int gr = m0 + wm * 64 + m * 16 + (ln >> 4) * 4 + j;
        p[m][j] += acc[m][n][j] * bf2f(Qb[((size_t)s * NB + gr) * DM + gc]);
      }
    }
  }
#pragma unroll
  for (int m = 0; m < 4; ++m)
#pragma unroll
    for (int j = 0; j < 4; ++j) {
      float v = p[m][j];
      v += __shfl_xor(v, 1, 64);
      v += __shfl_xor(v, 2, 64);
      v += __shfl_xor(v, 4, 64);
      v += __shfl_xor(v, 8, 64);
      p[m][j] = v;
    }
  if ((ln & 15) == 0) {
#pragma unroll
    for (int m = 0; m < 4; ++m)
#pragma unroll
      for (int j = 0; j < 4; ++j) {
        const int gr = m0 + wm * 64 + m * 16 + (ln >> 4) * 4 + j;
        wbuf[(((size_t)s * NB + gr) * 8 + h) * 4 + kp] = p[m][j] * 0.125f;
      }
  }
}

// V-projection for all 4 key positions fused: facc = sum_kp w[s,b,h,kp]*((x_kp Wv)_gc + bv)
// single bf16 write of ctxc [B][2048].
__global__ __launch_bounds__(256) void k_gemmv4(
    const u16* __restrict__ xcat, const u16* __restrict__ WvT_l,
    const float* __restrict__ bv_l, const float* __restrict__ wbuf,
    u16* __restrict__ ctxc)
{
  int bx, by, bz; remap(bx, by, bz); (void)bz;
  __shared__ alignas(16) u16 As[2 * 8192];
  __shared__ alignas(16) u16 Bs[2 * 8192];
  const int ln = threadIdx.x & 63;
  const int w = threadIdx.x >> 6;
  const int wm = w >> 1, wn = w & 1;
  const int m0 = bx * 128, n0 = by * 128;
  const int s  = n0 >> 9;
  const int hh = ((n0 >> 6) + wn) & 7;
  f32x4 facc[4][4] = {};
  for (int kp = 0; kp < 4; ++kp) {
    f32x4 acc[4][4] = {};
    gemm64(xcat + kp * DM, XW, WvT_l, DM, As, Bs, acc, bx, by);
    float wv[4][4];
#pragma unroll
    for (int m = 0; m < 4; ++m)
#pragma unroll
      for (int j = 0; j < 4; ++j) {
        const int gr = m0 + wm * 64 + m * 16 + (ln >> 4) * 4 + j;
        wv[m][j] = wbuf[(((size_t)s * NB + gr) * 8 + hh) * 4 + kp];
      }
#pragma unroll
    for (int n = 0; n < 4; ++n) {
      const float bvv = bv_l[n0 + wn * 64 + n * 16 + (ln & 15)];
#pragma unroll
      for (int m = 0; m < 4; ++m)
#pragma unroll
        for (int j = 0; j < 4; ++j)
          facc[m][n][j] += (acc[m][n][j] + bvv) * wv[m][j];
    }
  }
#pragma unroll
  for (int n = 0; n < 4; ++n) {
    const int gc = n0 + wn * 64 + n * 16 + (ln & 15);
#pragma unroll
    for (int m = 0; m < 4; ++m)
#pragma unroll
      for (int j = 0; j < 4; ++j) {
        const int gr = m0 + wm * 64 + m * 16 + (ln >> 4) * 4 + j;
        ctxc[(size_t)gr * XW + gc] = f2bf(facc[m][n][j]);
      }
  }
}

// softmax over kp in-place on wbuf [S][B][H][4]; optional write to attn0
__global__ __launch_bounds__(256) void k_softmax(
    float* __restrict__ wbuf, float* __restrict__ a0)
{
  const int t = blockIdx.x * 256 + threadIdx.x;   // (s*NB + b)*8 + h
  float4 v = ((const float4*)wbuf)[t];
  const float mx = fmaxf(fmaxf(v.x, v.y), fmaxf(v.z, v.w));
  float4 e;
  e.x = __expf(v.x - mx); e.y = __expf(v.y - mx);
  e.z = __expf(v.z - mx); e.w = __expf(v.w - mx);
  const float inv = 1.f / (e.x + e.y + e.z + e.w);
  e.x *= inv; e.y *= inv; e.z *= inv; e.w *= inv;
  ((float4*)wbuf)[t] = e;
  if (a0 != nullptr) {
    const int s = t >> 17, b = (t >> 3) & (NB - 1), h = t & 7;
    ((float4*)a0)[((size_t)b * NS + s) * 8 + h] = e;
  }
}

// in-place LayerNorm over each 512-wide stream block of xcat; wave per (b,s)
__global__ __launch_bounds__(256) void k_ln(
    u16* __restrict__ xcat, const float* __restrict__ g, const float* __restrict__ bb)
{
  const int ln = threadIdx.x & 63;
  const int row = blockIdx.x * 4 + (threadIdx.x >> 6);
  const int b = row >> 2, s = row & 3;
  u16* p = xcat + (size_t)b * XW + s * DM;
  float v[8];
  { uint4 t = ((const uint4*)p)[ln]; unpack8(t, v); }
  float sum = 0.f;
#pragma unroll
  for (int j = 0; j < 8; ++j) sum += v[j];
#pragma unroll
  for (int off = 1; off < 64; off <<= 1) sum += __shfl_xor(sum, off, 64);
  const float mu = sum * (1.f / DM);
  float s2 = 0.f;
#pragma unroll
  for (int j = 0; j < 8; ++j) { float d = v[j] - mu; s2 += d * d; }
#pragma unroll
  for (int off = 1; off < 64; off <<= 1) s2 += __shfl_xor(s2, off, 64);
  const float rs = rsqrtf(s2 * (1.f / DM) + EPSL);
  const int e0 = s * DM + ln * 8;
  float o[8];
#pragma unroll
  for (int j = 0; j < 8; ++j) o[j] = (v[j] - mu) * rs * g[e0 + j] + bb[e0 + j];
  ((uint4*)p)[ln] = pack8(o);
}

// pack 4 fp32 streams -> xcat bf16 [B][S*D]
__global__ void k_pack(const float* __restrict__ t0, const float* __restrict__ t1,
                       const float* __restrict__ t2, const float* __restrict__ t3,
                       u16* __restrict__ xcat)
{
  const int total = NB * XW / 8;
  for (int t = blockIdx.x * blockDim.x + threadIdx.x; t < total; t += gridDim.x * blockDim.x) {
    const int b = t >> 8;
    const int r = t & 255;
    const int s = r >> 6;
    const int d0 = (r & 63) * 8;
    const float* p = (s == 0) ? t0 : (s == 1) ? t1 : (s == 2) ? t2 : t3;
    float f[8];
#pragma unroll
    for (int j = 0; j < 8; ++j) f[j] = p[(size_t)b * DM + d0 + j];
    ((uint4*)xcat)[t] = pack8(f);
  }
}

// coalesced transpose + fp32->bf16 via LDS 32x32 tiles.
// grid (C/32, R/32, nb), block 256. src nb x [R][C] -> dst nb x [C][R].
__global__ __launch_bounds__(256) void k_tcvt(
    const float* __restrict__ src, u16* __restrict__ dst, int R, int C)
{
  __shared__ float tl[32][33];
  const int cx = blockIdx.x * 32, ry = blockIdx.y * 32;
  const size_t base = (size_t)blockIdx.z * R * C;
  const int lx = threadIdx.x & 31, ly = threadIdx.x >> 5;   // 8 rows per pass
#pragma unroll
  for (int i = 0; i < 32; i += 8)
    tl[ly + i][lx] = src[base + (size_t)(ry + ly + i) * C + cx + lx];
  __syncthreads();
#pragma unroll
  for (int i = 0; i < 32; i += 8)
    dst[base + (size_t)(cx + ly + i) * R + ry + lx] = f2bf(tl[lx][ly + i]);
}

extern "C" void kernel_launch(void* const* d_in, const int* in_sizes, int n_in,
                              void* d_out, int out_size, void* d_ws, size_t ws_size,
                              hipStream_t stream)
{
  (void)in_sizes; (void)n_in; (void)out_size;
  const float* t0  = (const float*)d_in[0];
  const float* t1  = (const float*)d_in[1];
  const float* t2  = (const float*)d_in[2];
  const float* t3  = (const float*)d_in[3];
  const float* Wq  = (const float*)d_in[4];
  const float* bq  = (const float*)d_in[5];
  const float* Wk  = (const float*)d_in[6];
  const float* Wv  = (const float*)d_in[8];
  const float* bv  = (const float*)d_in[9];
  const float* Wo  = (const float*)d_in[10];
  const float* bo  = (const float*)d_in[11];
  const float* lng = (const float*)d_in[12];
  const float* lnb = (const float*)d_in[13];
  const float* W1  = (const float*)d_in[14];
  const float* b1  = (const float*)d_in[15];
  const float* W2  = (const float*)d_in[16];
  const float* b2  = (const float*)d_in[17];
  const float* Wf1 = (const float*)d_in[18];
  const float* bf1 = (const float*)d_in[19];
  const float* Wf2 = (const float*)d_in[20];
  const float* bf2 = (const float*)d_in[21];

  size_t off = 0;
  char* ws = (char*)d_ws;
  auto take = [&](size_t n) { char* p = ws + off; off += (n + 255) & ~(size_t)255; return p; };
  u16* WqT  = (u16*)take(8ull * DM * DM * 2);        //  4 MiB
  u16* WkT  = (u16*)take(8ull * DM * DM * 2);        //  4
  u16* WvT  = (u16*)take(8ull * DM * DM * 2);        //  4
  u16* WoT  = (u16*)take(8ull * DM * DM * 2);        //  4
  u16* W1T  = (u16*)take(8ull * DM * FH * 2);        // 16
  u16* W2T  = (u16*)take(8ull * FH * DM * 2);        // 16
  u16* Wf1T = (u16*)take((size_t)XW * 1024 * 2);     //  4
  u16* Wf2T = (u16*)take((size_t)1024 * DM * 2);     //  1
  u16* xcat = (u16*)take((size_t)NB * XW * 2);       // 64
  char* U1  = take((size_t)NB * XW * 2);             // 64: Qb | ctxc | ffn1 | y1
  float* wbuf = (float*)take(4ull * NB * 8 * 4 * 4); //  8
  const size_t needed = off;                          // ~189 MiB

  u16* Qb   = (u16*)U1;   // [S][B][512]
  u16* ctxc = (u16*)U1;   // [B][2048]
  u16* ffn1 = (u16*)U1;   // [B][2048] per stream
  u16* y1   = (u16*)U1;   // [B][1024]
  float* attn0 = (float*)d_out + (size_t)NB * DM;

  if (needed > ws_size) return;  // diagnostic: clean fail instead of GPU fault

  // weight prep: fp32 -> bf16, transposed to [N][K] (coalesced LDS transpose)
  k_tcvt<<<dim3(16, 16, 8), dim3(256), 0, stream>>>(Wq, WqT, DM, DM);
  k_tcvt<<<dim3(16, 16, 8), dim3(256), 0, stream>>>(Wk, WkT, DM, DM);
  k_tcvt<<<dim3(16, 16, 8), dim3(256), 0, stream>>>(Wv, WvT, DM, DM);
  k_tcvt<<<dim3(16, 16, 8), dim3(256), 0, stream>>>(Wo, WoT, DM, DM);
  k_tcvt<<<dim3(64, 16, 8), dim3(256), 0, stream>>>(W1, W1T, DM, FH);
  k_tcvt<<<dim3(16, 64, 8), dim3(256), 0, stream>>>(W2, W2T, FH, DM);
  k_tcvt<<<dim3(32, 64, 1), dim3(256), 0, stream>>>(Wf1, Wf1T, XW, 1024);
  k_tcvt<<<dim3(16, 32, 1), dim3(256), 0, stream>>>(Wf2, Wf2T, 1024, DM);
  k_pack<<<dim3(2048), dim3(256), 0, stream>>>(t0, t1, t2, t3, xcat);

  const long WSQ = (long)DM * DM;
  for (int ly = 0; ly < 2; ++ly) {
    const u16* WqT_l = WqT + (size_t)ly * 4 * WSQ;
    const u16* WkT_l = WkT + (size_t)ly * 4 * WSQ;
    const u16* WvT_l = WvT + (size_t)ly * 4 * WSQ;
    const u16* WoT_l = WoT + (size_t)ly * 4 * WSQ;
    // Q projection, all streams in one launch (z = s)
    k_gemm<false, false, false><<<dim3(128, 4, 4), dim3(256), 0, stream>>>(
        xcat, XW, DM, WqT_l, WSQ, bq + (size_t)ly * XW, DM,
        nullptr, 0, 0, Qb, DM, (long)NB * DM, DM);
    // K projection + fused q.k dot, all (s,kp) in one launch
    k_kdot<<<dim3(128, 4, 16), dim3(256), 0, stream>>>(xcat, WkT_l, Qb, wbuf);
    k_softmax<<<dim3(4 * NB * 8 / 256), dim3(256), 0, stream>>>(
        wbuf, (ly == 0) ? attn0 : (float*)nullptr);
    // V projection (N=2048 over streams), all 4 kp fused, fp32 reg accumulate
    k_gemmv4<<<dim3(128, 16), dim3(256), 0, stream>>>(
        xcat, WvT_l, bv + (size_t)ly * XW, wbuf, ctxc);
    // O projection, residual-fused, in-place into xcat (z = s)
    k_gemm<false, true, false><<<dim3(128, 4, 4), dim3(256), 0, stream>>>(
        ctxc, XW, DM, WoT_l, WSQ, bo + (size_t)ly * XW, DM,
        xcat, XW, DM, xcat, XW, DM, DM);
    k_ln<<<dim3(NB), dim3(256), 0, stream>>>(xcat, lng + ly * XW, lnb + ly * XW);
    // FFN per stream, residual-fused, in-place into xcat
    for (int s = 0; s < NS; ++s) {
      const size_t wsl = (size_t)(ly * 4 + s);
      k_gemm<true, false, false><<<dim3(128, 16, 1), dim3(256), 0, stream>>>(
          xcat + s * DM, XW, 0, W1T + wsl * (size_t)DM * FH, 0, b1 + wsl * FH, 0,
          nullptr, 0, 0, ffn1, FH, 0, DM);
      k_gemm<false, true, false><<<dim3(128, 4, 1), dim3(256), 0, stream>>>(
          ffn1, FH, 0, W2T + wsl * (size_t)FH * DM, 0, b2 + wsl * DM, 0,
          xcat + s * DM, XW, 0, xcat + s * DM, XW, 0, FH);
    }
  }
  // final fusion MLP
  k_gemm<true, false, false><<<dim3(128, 8, 1), dim3(256), 0, stream>>>(
      xcat, XW, 0, Wf1T, 0, bf1, 0, nullptr, 0, 0, y1, 1024, 0, XW);
  k_gemm<false, false, true><<<dim3(128, 4, 1), dim3(256), 0, stream>>>(
      y1, 1024, 0, Wf2T, 0, bf2, 0, nullptr, 0, 0, d_out, DM, 0, 1024);
}

// Round 9
// 3380.085 us; speedup vs baseline: 1.2064x; 1.0304x over previous
//
#include <hip/hip_runtime.h>
#include <stdint.h>

typedef unsigned short u16;
typedef __bf16 bf16x8 __attribute__((ext_vector_type(8)));
typedef float f32x4 __attribute__((ext_vector_type(4)));

constexpr int NB = 16384;        // batch tokens
constexpr int DM = 512;          // model dim
constexpr int NS = 4;            // streams
constexpr int FH = 2048;         // FFN hidden
constexpr int XW = NS * DM;      // 2048 concat width
constexpr float EPSL = 1e-5f;

__device__ __forceinline__ float bf2f(u16 u) { return __uint_as_float(((uint32_t)u) << 16); }
__device__ __forceinline__ u16 f2bf(float f) {
  uint32_t u = __float_as_uint(f);
  u += 0x7fffu + ((u >> 16) & 1u);
  return (u16)(u >> 16);
}
__device__ __forceinline__ void unpack8(uint4 p, float* f) {
  f[0] = __uint_as_float(p.x << 16); f[1] = __uint_as_float(p.x & 0xffff0000u);
  f[2] = __uint_as_float(p.y << 16); f[3] = __uint_as_float(p.y & 0xffff0000u);
  f[4] = __uint_as_float(p.z << 16); f[5] = __uint_as_float(p.z & 0xffff0000u);
  f[6] = __uint_as_float(p.w << 16); f[7] = __uint_as_float(p.w & 0xffff0000u);
}
__device__ __forceinline__ uint4 pack8(const float* f) {
  uint4 r;
  r.x = (uint32_t)f2bf(f[0]) | ((uint32_t)f2bf(f[1]) << 16);
  r.y = (uint32_t)f2bf(f[2]) | ((uint32_t)f2bf(f[3]) << 16);
  r.z = (uint32_t)f2bf(f[4]) | ((uint32_t)f2bf(f[5]) << 16);
  r.w = (uint32_t)f2bf(f[6]) | ((uint32_t)f2bf(f[7]) << 16);
  return r;
}
__device__ __forceinline__ void gl_lds16(const void* g, void* l) {
  __builtin_amdgcn_global_load_lds((const __attribute__((address_space(1))) void*)g,
                                   (__attribute__((address_space(3))) void*)l, 16, 0, 0);
}

// XCD-aware bijective remap. gx%8==0 required (all launches satisfy).
__device__ __forceinline__ void remap(int& bx, int& by, int& bz) {
  const int gx = gridDim.x, gy = gridDim.y;
  const int fl = (blockIdx.z * gy + blockIdx.y) * gx + blockIdx.x;
  const int xcd = fl & 7;
  const int t = fl >> 3;
  const int bw = gx >> 3;
  bx = xcd * bw + t % bw;
  const int u = t / bw;
  by = u % gy;
  bz = u / gy;
}

// ---- 128x128 GEMM core, BK=32, 4 buffers, DEPTH-3 counted-vmcnt pipeline ----
// r5 ledger extended one deeper: stage tile t+3 at the TOP of iteration t;
// steady wait vmcnt(8) retires tile t+1 (issued 3 iterations back -> ~1000cy
// slack, covers HBM first-touch). Tail waits 8->4->0. Buffer (t+3)&3 was
// freed by the barrier ending iteration t-1. Loop body has no other vmem;
// epilogue vmem is consumed before any next call (compiler drains it).
// Swizzle (proven r4): global source 16B-block ^= key, reads apply same XOR.
__device__ __forceinline__ void gemm_cv(
    const u16* __restrict__ A, int lda,
    const u16* __restrict__ Bt, int K,    // Bt row stride == K
    u16* As, u16* Bs, f32x4 (&acc)[4][4], int bx, int by)
{
  const int tid = threadIdx.x;
  const int ln = tid & 63;
  const int w  = tid >> 6;
  const int wm = w >> 1, wn = w & 1;
  const int m0 = bx * 128;
  const int n0 = by * 128;
  const int grow = ln >> 2;                                  // row within 16-chunk
  const int gcol = ((ln & 3) ^ ((ln >> 3) & 3)) * 8;         // swizzled src 16B-block
  const u16* Ab = A  + (size_t)(m0 + w * 32 + grow) * lda + gcol;
  const u16* Bb = Bt + (size_t)(n0 + w * 32 + grow) * K   + gcol;

  auto stage = [&](int buf, int k0) {
#pragma unroll
    for (int i = 0; i < 2; ++i) {
      gl_lds16(Ab + (size_t)i * 16 * lda + k0, &As[buf * 4096 + (w * 32 + i * 16) * 32]);
      gl_lds16(Bb + (size_t)i * 16 * K   + k0, &Bs[buf * 4096 + (w * 32 + i * 16) * 32]);
    }
  };

  __syncthreads();               // protect LDS reuse across successive calls
  const int nt = K >> 5;
  stage(0, 0);
  if (nt > 1) stage(1, 32);
  if (nt > 2) stage(2, 64);
  if (nt > 2)      { asm volatile("s_waitcnt vmcnt(8)" ::: "memory"); }
  else if (nt > 1) { asm volatile("s_waitcnt vmcnt(4)" ::: "memory"); }
  else             { asm volatile("s_waitcnt vmcnt(0)" ::: "memory"); }
  __builtin_amdgcn_s_barrier();
  asm volatile("" ::: "memory");

  const int cb = ((ln >> 4) ^ (((ln & 15) >> 1) & 3)) * 8;   // swizzled read blk
  for (int t = 0; t < nt; ++t) {
    const int cur = t & 3;
    if (t + 3 < nt) stage((t + 3) & 3, (t + 3) * 32);        // issued FIRST
    bf16x8 af[4], bfv[4];
#pragma unroll
    for (int m = 0; m < 4; ++m) {
      af[m]  = *(const bf16x8*)&As[cur * 4096 + (wm * 64 + m * 16 + (ln & 15)) * 32 + cb];
      bfv[m] = *(const bf16x8*)&Bs[cur * 4096 + (wn * 64 + m * 16 + (ln & 15)) * 32 + cb];
    }
#pragma unroll
    for (int m = 0; m < 4; ++m)
#pragma unroll
      for (int n = 0; n < 4; ++n)
        acc[m][n] = __builtin_amdgcn_mfma_f32_16x16x32_bf16(af[m], bfv[n], acc[m][n], 0, 0, 0);
    if (t + 3 < nt)      asm volatile("s_waitcnt vmcnt(8)" ::: "memory");
    else if (t + 2 < nt) asm volatile("s_waitcnt vmcnt(4)" ::: "memory");
    else if (t + 1 < nt) asm volatile("s_waitcnt vmcnt(0)" ::: "memory");
    else break;
    __builtin_amdgcn_s_barrier();
    asm volatile("" ::: "memory");
  }
  asm volatile("" ::: "memory");   // fence: epilogue vmem must not hoist into loop
}

// generic GEMM with per-z offsets: C = A*Bt^T + bias [+Rsd][ReLU]
template<bool RELU, bool RESID, bool OUTF32>
__global__ __launch_bounds__(256) void k_gemm(
    const u16* __restrict__ A, int lda, long aZ,
    const u16* __restrict__ Bt, long bZ,
    const float* __restrict__ bias, long biasZ,
    const u16* __restrict__ Rsd, int ldr, long rZ,
    void* __restrict__ Cp, int ldc, long cZ, int K)
{
  int bx, by, bz; remap(bx, by, bz);
  A += (long)bz * aZ; Bt += (long)bz * bZ; bias += (long)bz * biasZ;
  __shared__ alignas(16) u16 As[4 * 4096];
  __shared__ alignas(16) u16 Bs[4 * 4096];
  f32x4 acc[4][4] = {};
  gemm_cv(A, lda, Bt, K, As, Bs, acc, bx, by);
  const int ln = threadIdx.x & 63;
  const int w = threadIdx.x >> 6;
  const int wm = w >> 1, wn = w & 1;
  const int m0 = bx * 128, n0 = by * 128;
#pragma unroll
  for (int n = 0; n < 4; ++n) {
    const int gc = n0 + wn * 64 + n * 16 + (ln & 15);
    const float bv = bias[gc];
#pragma unroll
    for (int m = 0; m < 4; ++m) {
#pragma unroll
      for (int j = 0; j < 4; ++j) {
        const int gr = m0 + wm * 64 + m * 16 + (ln >> 4) * 4 + j;
        float v = acc[m][n][j] + bv;
        if constexpr (RESID) v += bf2f(Rsd[(long)bz * rZ + (size_t)gr * ldr + gc]);
        if constexpr (RELU)  v = v > 0.f ? v : 0.f;
        if constexpr (OUTF32) ((float*)Cp)[(long)bz * cZ + (size_t)gr * ldc + gc] = v;
        else                  ((u16*)Cp)[(long)bz * cZ + (size_t)gr * ldc + gc] = f2bf(v);
      }
    }
  }
}

// K-projection GEMM with fused q.k dot epilogue. z = s*4+kp.
// Writes raw scores (x1/8) to wbuf[s][b][h][kp]. K-bias softmax-invariant.
__global__ __launch_bounds__(256) void k_kdot(
    const u16* __restrict__ xcat, const u16* __restrict__ WkT_l,
    const u16* __restrict__ Qb, float* __restrict__ wbuf)
{
  int bx, by, bz; remap(bx, by, bz);
  const int s = bz >> 2, kp = bz & 3;
  __shared__ alignas(16) u16 As[4 * 4096];
  __shared__ alignas(16) u16 Bs[4 * 4096];
  f32x4 acc[4][4] = {};
  gemm_cv(xcat + kp * DM, XW, WkT_l + (size_t)s * DM * DM, DM, As, Bs, acc, bx, by);
  const int ln = threadIdx.x & 63;
  const int w = threadIdx.x >> 6;
  const int wm = w >> 1, wn = w & 1;
  const int m0 = bx * 128, n0 = by * 128;
  const int h = (n0 >> 6) + wn;
  float p[4][4];
#pragma unroll
  for (int m = 0; m < 4; ++m)
#pragma unroll
    for (int j = 0; j < 4; ++j) p[m][j] = 0.f;
#pragma unroll
  for (int n = 0; n < 4; ++n) {
    const int gc = n0 + wn * 64 + n * 16 + (ln & 15);
#pragma unroll
    for (int m = 0; m < 4; ++m) {
#pragma unroll
      for (int j = 0; j < 4; ++j) {
        const int gr = m0 + wm * 64 + m * 16 + (ln >> 4) * 4 + j;
        p[m][j] += acc[m][n][j] * bf2f(Qb[((size_t)s * NB + gr) * DM + gc]);
      }
    }
  }
#pragma unroll
  for (int m = 0; m < 4; ++m)
#pragma unroll
    for (int j = 0; j < 4; ++j) {
      float v = p[m][j];
      v += __shfl_xor(v, 1, 64);
      v += __shfl_xor(v, 2, 64);
      v += __shfl_xor(v, 4, 64);
      v += __shfl_xor(v, 8, 64);
      p[m][j] = v;
    }
  if ((ln & 15) == 0) {
#pragma unroll
    for (int m = 0; m < 4; ++m)
#pragma unroll
      for (int j = 0; j < 4; ++j) {
        const int gr = m0 + wm * 64 + m * 16 + (ln >> 4) * 4 + j;
        wbuf[(((size_t)s * NB + gr) * 8 + h) * 4 + kp] = p[m][j] * 0.125f;
      }
  }
}

// V-projection for all 4 key positions fused: facc = sum_kp w[s,b,h,kp]*((x_kp Wv)_gc + bv)
// single bf16 write of ctxc [B][2048]; wbuf/bias reads consumed between calls.
__global__ __launch_bounds__(256) void k_gemmv4(
    const u16* __restrict__ xcat, const u16* __restrict__ WvT_l,
    const float* __restrict__ bv_l, const float* __restrict__ wbuf,
    u16* __restrict__ ctxc)
{
  int bx, by, bz; remap(bx, by, bz); (void)bz;
  __shared__ alignas(16) u16 As[4 * 4096];
  __shared__ alignas(16) u16 Bs[4 * 4096];
  const int ln = threadIdx.x & 63;
  const int w = threadIdx.x >> 6;
  const int wm = w >> 1, wn = w & 1;
  const int m0 = bx * 128, n0 = by * 128;
  const int s  = n0 >> 9;
  const int hh = ((n0 >> 6) + wn) & 7;
  f32x4 facc[4][4] = {};
  for (int kp = 0; kp < 4; ++kp) {
    f32x4 acc[4][4] = {};
    gemm_cv(xcat + kp * DM, XW, WvT_l, DM, As, Bs, acc, bx, by);
    float wv[4][4];
#pragma unroll
    for (int m = 0; m < 4; ++m)
#pragma unroll
      for (int j = 0; j < 4; ++j) {
        const int gr = m0 + wm * 64 + m * 16 + (ln >> 4) * 4 + j;
        wv[m][j] = wbuf[(((size_t)s * NB + gr) * 8 + hh) * 4 + kp];
      }
#pragma unroll
    for (int n = 0; n < 4; ++n) {
      const float bvv = bv_l[n0 + wn * 64 + n * 16 + (ln & 15)];
#pragma unroll
      for (int m = 0; m < 4; ++m)
#pragma unroll
        for (int j = 0; j < 4; ++j)
          facc[m][n][j] += (acc[m][n][j] + bvv) * wv[m][j];
    }
  }
#pragma unroll
  for (int n = 0; n < 4; ++n) {
    const int gc = n0 + wn * 64 + n * 16 + (ln & 15);
#pragma unroll
    for (int m = 0; m < 4; ++m)
#pragma unroll
      for (int j = 0; j < 4; ++j) {
        const int gr = m0 + wm * 64 + m * 16 + (ln >> 4) * 4 + j;
        ctxc[(size_t)gr * XW + gc] = f2bf(facc[m][n][j]);
      }
  }
}

// softmax over kp in-place on wbuf [S][B][H][4]; optional write to attn0
__global__ __launch_bounds__(256) void k_softmax(
    float* __restrict__ wbuf, float* __restrict__ a0)
{
  const int t = blockIdx.x * 256 + threadIdx.x;   // (s*NB + b)*8 + h
  float4 v = ((const float4*)wbuf)[t];
  const float mx = fmaxf(fmaxf(v.x, v.y), fmaxf(v.z, v.w));
  float4 e;
  e.x = __expf(v.x - mx); e.y = __expf(v.y - mx);
  e.z = __expf(v.z - mx); e.w = __expf(v.w - mx);
  const float inv = 1.f / (e.x + e.y + e.z + e.w);
  e.x *= inv; e.y *= inv; e.z *= inv; e.w *= inv;
  ((float4*)wbuf)[t] = e;
  if (a0 != nullptr) {
    const int s = t >> 17, b = (t >> 3) & (NB - 1), h = t & 7;
    ((float4*)a0)[((size_t)b * NS + s) * 8 + h] = e;
  }
}

// in-place LayerNorm over each 512-wide stream block of xcat; wave per (b,s)
__global__ __launch_bounds__(256) void k_ln(
    u16* __restrict__ xcat, const float* __restrict__ g, const float* __restrict__ bb)
{
  const int ln = threadIdx.x & 63;
  const int row = blockIdx.x * 4 + (threadIdx.x >> 6);
  const int b = row >> 2, s = row & 3;
  u16* p = xcat + (size_t)b * XW + s * DM;
  float v[8];
  { uint4 t = ((const uint4*)p)[ln]; unpack8(t, v); }
  float sum = 0.f;
#pragma unroll
  for (int j = 0; j < 8; ++j) sum += v[j];
#pragma unroll
  for (int off = 1; off < 64; off <<= 1) sum += __shfl_xor(sum, off, 64);
  const float mu = sum * (1.f / DM);
  float s2 = 0.f;
#pragma unroll
  for (int j = 0; j < 8; ++j) { float d = v[j] - mu; s2 += d * d; }
#pragma unroll
  for (int off = 1; off < 64; off <<= 1) s2 += __shfl_xor(s2, off, 64);
  const float rs = rsqrtf(s2 * (1.f / DM) + EPSL);
  const int e0 = s * DM + ln * 8;
  float o[8];
#pragma unroll
  for (int j = 0; j < 8; ++j) o[j] = (v[j] - mu) * rs * g[e0 + j] + bb[e0 + j];
  ((uint4*)p)[ln] = pack8(o);
}

// pack 4 fp32 streams -> xcat bf16 [B][S*D]
__global__ void k_pack(const float* __restrict__ t0, const float* __restrict__ t1,
                       const float* __restrict__ t2, const float* __restrict__ t3,
                       u16* __restrict__ xcat)
{
  const int total = NB * XW / 8;
  for (int t = blockIdx.x * blockDim.x + threadIdx.x; t < total; t += gridDim.x * blockDim.x) {
    const int b = t >> 8;
    const int r = t & 255;
    const int s = r >> 6;
    const int d0 = (r & 63) * 8;
    const float* p = (s == 0) ? t0 : (s == 1) ? t1 : (s == 2) ? t2 : t3;
    float f[8];
#pragma unroll
    for (int j = 0; j < 8; ++j) f[j] = p[(size_t)b * DM + d0 + j];
    ((uint4*)xcat)[t] = pack8(f);
  }
}

// coalesced transpose + fp32->bf16 via LDS 32x32 tiles.
// grid (C/32, R/32, nb), block 256. src nb x [R][C] -> dst nb x [C][R].
__global__ __launch_bounds__(256) void k_tcvt(
    const float* __restrict__ src, u16* __restrict__ dst, int R, int C)
{
  __shared__ float tl[32][33];
  const int cx = blockIdx.x * 32, ry = blockIdx.y * 32;
  const size_t base = (size_t)blockIdx.z * R * C;
  const int lx = threadIdx.x & 31, ly = threadIdx.x >> 5;   // 8 rows per pass
#pragma unroll
  for (int i = 0; i < 32; i += 8)
    tl[ly + i][lx] = src[base + (size_t)(ry + ly + i) * C + cx + lx];
  __syncthreads();
#pragma unroll
  for (int i = 0; i < 32; i += 8)
    dst[base + (size_t)(cx + ly + i) * R + ry + lx] = f2bf(tl[lx][ly + i]);
}

extern "C" void kernel_launch(void* const* d_in, const int* in_sizes, int n_in,
                              void* d_out, int out_size, void* d_ws, size_t ws_size,
                              hipStream_t stream)
{
  (void)in_sizes; (void)n_in; (void)out_size;
  const float* t0  = (const float*)d_in[0];
  const float* t1  = (const float*)d_in[1];
  const float* t2  = (const float*)d_in[2];
  const float* t3  = (const float*)d_in[3];
  const float* Wq  = (const float*)d_in[4];
  const float* bq  = (const float*)d_in[5];
  const float* Wk  = (const float*)d_in[6];
  const float* Wv  = (const float*)d_in[8];
  const float* bv  = (const float*)d_in[9];
  const float* Wo  = (const float*)d_in[10];
  const float* bo  = (const float*)d_in[11];
  const float* lng = (const float*)d_in[12];
  const float* lnb = (const float*)d_in[13];
  const float* W1  = (const float*)d_in[14];
  const float* b1  = (const float*)d_in[15];
  const float* W2  = (const float*)d_in[16];
  const float* b2  = (const float*)d_in[17];
  const float* Wf1 = (const float*)d_in[18];
  const float* bf1 = (const float*)d_in[19];
  const float* Wf2 = (const float*)d_in[20];
  const float* bf2 = (const float*)d_in[21];

  size_t off = 0;
  char* ws = (char*)d_ws;
  auto take = [&](size_t n) { char* p = ws + off; off += (n + 255) & ~(size_t)255; return p; };
  u16* WqT  = (u16*)take(8ull * DM * DM * 2);        //  4 MiB
  u16* WkT  = (u16*)take(8ull * DM * DM * 2);        //  4
  u16* WvT  = (u16*)take(8ull * DM * DM * 2);        //  4
  u16* WoT  = (u16*)take(8ull * DM * DM * 2);        //  4
  u16* W1T  = (u16*)take(8ull * DM * FH * 2);        // 16
  u16* W2T  = (u16*)take(8ull * FH * DM * 2);        // 16
  u16* Wf1T = (u16*)take((size_t)XW * 1024 * 2);     //  4
  u16* Wf2T = (u16*)take((size_t)1024 * DM * 2);     //  1
  u16* xcat = (u16*)take((size_t)NB * XW * 2);       // 64
  char* U1  = take((size_t)NB * XW * 2);             // 64: Qb | ctxc | ffn1 | y1
  float* wbuf = (float*)take(4ull * NB * 8 * 4 * 4); //  8
  const size_t needed = off;                          // ~189 MiB

  u16* Qb   = (u16*)U1;   // [S][B][512]
  u16* ctxc = (u16*)U1;   // [B][2048]
  u16* ffn1 = (u16*)U1;   // [B][2048] per stream
  u16* y1   = (u16*)U1;   // [B][1024]
  float* attn0 = (float*)d_out + (size_t)NB * DM;

  if (needed > ws_size) return;  // diagnostic: clean fail instead of GPU fault

  // weight prep: fp32 -> bf16, transposed to [N][K] (coalesced LDS transpose)
  k_tcvt<<<dim3(16, 16, 8), dim3(256), 0, stream>>>(Wq, WqT, DM, DM);
  k_tcvt<<<dim3(16, 16, 8), dim3(256), 0, stream>>>(Wk, WkT, DM, DM);
  k_tcvt<<<dim3(16, 16, 8), dim3(256), 0, stream>>>(Wv, WvT, DM, DM);
  k_tcvt<<<dim3(16, 16, 8), dim3(256), 0, stream>>>(Wo, WoT, DM, DM);
  k_tcvt<<<dim3(64, 16, 8), dim3(256), 0, stream>>>(W1, W1T, DM, FH);
  k_tcvt<<<dim3(16, 64, 8), dim3(256), 0, stream>>>(W2, W2T, FH, DM);
  k_tcvt<<<dim3(32, 64, 1), dim3(256), 0, stream>>>(Wf1, Wf1T, XW, 1024);
  k_tcvt<<<dim3(16, 32, 1), dim3(256), 0, stream>>>(Wf2, Wf2T, 1024, DM);
  k_pack<<<dim3(2048), dim3(256), 0, stream>>>(t0, t1, t2, t3, xcat);

  const long WSQ = (long)DM * DM;
  for (int ly = 0; ly < 2; ++ly) {
    const u16* WqT_l = WqT + (size_t)ly * 4 * WSQ;
    const u16* WkT_l = WkT + (size_t)ly * 4 * WSQ;
    const u16* WvT_l = WvT + (size_t)ly * 4 * WSQ;
    const u16* WoT_l = WoT + (size_t)ly * 4 * WSQ;
    // Q projection, all streams in one launch (z = s)
    k_gemm<false, false, false><<<dim3(128, 4, 4), dim3(256), 0, stream>>>(
        xcat, XW, DM, WqT_l, WSQ, bq + (size_t)ly * XW, DM,
        nullptr, 0, 0, Qb, DM, (long)NB * DM, DM);
    // K projection + fused q.k dot, all (s,kp) in one launch
    k_kdot<<<dim3(128, 4, 16), dim3(256), 0, stream>>>(xcat, WkT_l, Qb, wbuf);
    k_softmax<<<dim3(4 * NB * 8 / 256), dim3(256), 0, stream>>>(
        wbuf, (ly == 0) ? attn0 : (float*)nullptr);
    // V projection (N=2048 over streams), all 4 kp fused, fp32 reg accumulate
    k_gemmv4<<<dim3(128, 16), dim3(256), 0, stream>>>(
        xcat, WvT_l, bv + (size_t)ly * XW, wbuf, ctxc);
    // O projection, residual-fused, in-place into xcat (z = s)
    k_gemm<false, true, false><<<dim3(128, 4, 4), dim3(256), 0, stream>>>(
        ctxc, XW, DM, WoT_l, WSQ, bo + (size_t)ly * XW, DM,
        xcat, XW, DM, xcat, XW, DM, DM);
    k_ln<<<dim3(NB), dim3(256), 0, stream>>>(xcat, lng + ly * XW, lnb + ly * XW);
    // FFN per stream, residual-fused, in-place into xcat
    for (int s = 0; s < NS; ++s) {
      const size_t wsl = (size_t)(ly * 4 + s);
      k_gemm<true, false, false><<<dim3(128, 16, 1), dim3(256), 0, stream>>>(
          xcat + s * DM, XW, 0, W1T + wsl * (size_t)DM * FH, 0, b1 + wsl * FH, 0,
          nullptr, 0, 0, ffn1, FH, 0, DM);
      k_gemm<false, true, false><<<dim3(128, 4, 1), dim3(256), 0, stream>>>(
          ffn1, FH, 0, W2T + wsl * (size_t)FH * DM, 0, b2 + wsl * DM, 0,
          xcat + s * DM, XW, 0, xcat + s * DM, XW, 0, FH);
    }
  }
  // final fusion MLP
  k_gemm<true, false, false><<<dim3(128, 8, 1), dim3(256), 0, stream>>>(
      xcat, XW, 0, Wf1T, 0, bf1, 0, nullptr, 0, 0, y1, 1024, 0, XW);
  k_gemm<false, false, true><<<dim3(128, 4, 1), dim3(256), 0, stream>>>(
      y1, 1024, 0, Wf2T, 0, bf2, 0, nullptr, 0, 0, d_out, DM, 0, 1024);
}

// Round 10
// 2445.218 us; speedup vs baseline: 1.6676x; 1.3823x over previous
//
#include <hip/hip_runtime.h>
#include <stdint.h>

typedef unsigned short u16;
typedef __bf16 bf16x8 __attribute__((ext_vector_type(8)));
typedef float f32x4 __attribute__((ext_vector_type(4)));

constexpr int NB = 16384;        // batch tokens
constexpr int DM = 512;          // model dim
constexpr int NS = 4;            // streams
constexpr int FH = 2048;         // FFN hidden
constexpr int XW = NS * DM;      // 2048 concat width
constexpr float EPSL = 1e-5f;

__device__ __forceinline__ float bf2f(u16 u) { return __uint_as_float(((uint32_t)u) << 16); }
__device__ __forceinline__ u16 f2bf(float f) {
  uint32_t u = __float_as_uint(f);
  u += 0x7fffu + ((u >> 16) & 1u);
  return (u16)(u >> 16);
}
__device__ __forceinline__ void unpack8(uint4 p, float* f) {
  f[0] = __uint_as_float(p.x << 16); f[1] = __uint_as_float(p.x & 0xffff0000u);
  f[2] = __uint_as_float(p.y << 16); f[3] = __uint_as_float(p.y & 0xffff0000u);
  f[4] = __uint_as_float(p.z << 16); f[5] = __uint_as_float(p.z & 0xffff0000u);
  f[6] = __uint_as_float(p.w << 16); f[7] = __uint_as_float(p.w & 0xffff0000u);
}
__device__ __forceinline__ uint4 pack8(const float* f) {
  uint4 r;
  r.x = (uint32_t)f2bf(f[0]) | ((uint32_t)f2bf(f[1]) << 16);
  r.y = (uint32_t)f2bf(f[2]) | ((uint32_t)f2bf(f[3]) << 16);
  r.z = (uint32_t)f2bf(f[4]) | ((uint32_t)f2bf(f[5]) << 16);
  r.w = (uint32_t)f2bf(f[6]) | ((uint32_t)f2bf(f[7]) << 16);
  return r;
}
__device__ __forceinline__ void gl_lds16(const void* g, void* l) {
  __builtin_amdgcn_global_load_lds((const __attribute__((address_space(1))) void*)g,
                                   (__attribute__((address_space(3))) void*)l, 16, 0, 0);
}

// XCD-aware bijective remap. gx%8==0 required (all launches satisfy).
__device__ __forceinline__ void remap(int& bx, int& by, int& bz) {
  const int gx = gridDim.x, gy = gridDim.y;
  const int fl = (blockIdx.z * gy + blockIdx.y) * gx + blockIdx.x;
  const int xcd = fl & 7;
  const int t = fl >> 3;
  const int bw = gx >> 3;
  bx = xcd * bw + t % bw;
  const int u = t / bw;
  by = u % gy;
  bz = u / gy;
}

// ---- counted-vmcnt 3-buffer GEMM core: 128x128 tile, BK=32, 256 threads ----
// (champion r5 core, byte-identical) LDS write-linear for global_load_lds;
// GLOBAL source 16B-block pre-permuted blk^=(row>>1)&3, reads apply the same
// XOR -> even bank spread (conflict-free). Pipeline: stage tile t+2 during
// compute of t; vmcnt(4) + raw s_barrier; loop body has no other vmem.
__device__ __forceinline__ void gemm_cv(
    const u16* __restrict__ A, int lda,
    const u16* __restrict__ Bt, int K,    // Bt row stride == K
    u16* As, u16* Bs, f32x4 (&acc)[4][4], int bx, int by)
{
  const int tid = threadIdx.x;
  const int ln = tid & 63;
  const int w  = tid >> 6;
  const int wm = w >> 1, wn = w & 1;
  const int m0 = bx * 128;
  const int n0 = by * 128;
  const int grow = ln >> 2;                                  // row within 16-chunk
  const int gcol = ((ln & 3) ^ ((ln >> 3) & 3)) * 8;         // swizzled src 16B-block
  const u16* Ab = A  + (size_t)(m0 + w * 32 + grow) * lda + gcol;
  const u16* Bb = Bt + (size_t)(n0 + w * 32 + grow) * K   + gcol;

  auto stage = [&](int buf, int k0) {
#pragma unroll
    for (int i = 0; i < 2; ++i) {
      gl_lds16(Ab + (size_t)i * 16 * lda + k0, &As[buf * 4096 + (w * 32 + i * 16) * 32]);
      gl_lds16(Bb + (size_t)i * 16 * K   + k0, &Bs[buf * 4096 + (w * 32 + i * 16) * 32]);
    }
  };

  __syncthreads();               // protect LDS reuse across successive calls
  const int nt = K >> 5;
  stage(0, 0);
  if (nt > 1) {
    stage(1, 32);
    asm volatile("s_waitcnt vmcnt(4)" ::: "memory");
  } else {
    asm volatile("s_waitcnt vmcnt(0)" ::: "memory");
  }
  __builtin_amdgcn_s_barrier();
  asm volatile("" ::: "memory");

  const int rx = ((ln & 15) >> 1) & 3;   // per-row read XOR
  const int qb = ln >> 4;
  const int cb = (qb ^ rx) * 8;          // swizzled read 16B-block (elems)
  int cur = 0, nxt2 = 2;
  for (int t = 0; t < nt; ++t) {
    bf16x8 af[4], bfv[4];
#pragma unroll
    for (int m = 0; m < 4; ++m) {
      af[m]  = *(const bf16x8*)&As[cur * 4096 + (wm * 64 + m * 16 + (ln & 15)) * 32 + cb];
      bfv[m] = *(const bf16x8*)&Bs[cur * 4096 + (wn * 64 + m * 16 + (ln & 15)) * 32 + cb];
    }
#pragma unroll
    for (int m = 0; m < 4; ++m)
#pragma unroll
      for (int n = 0; n < 4; ++n)
        acc[m][n] = __builtin_amdgcn_mfma_f32_16x16x32_bf16(af[m], bfv[n], acc[m][n], 0, 0, 0);
    if (t + 2 < nt) {
      stage(nxt2, (t + 2) * 32);
      asm volatile("s_waitcnt vmcnt(4)" ::: "memory");   // tile t+1 ready, t+2 in flight
      __builtin_amdgcn_s_barrier();
      asm volatile("" ::: "memory");
    } else if (t + 1 < nt) {
      asm volatile("s_waitcnt vmcnt(0)" ::: "memory");   // drain last tile
      __builtin_amdgcn_s_barrier();
      asm volatile("" ::: "memory");
    }
    cur = cur + 1;  if (cur == 3)  cur = 0;
    nxt2 = nxt2 + 1; if (nxt2 == 3) nxt2 = 0;
  }
  asm volatile("" ::: "memory");   // fence: epilogue vmem must not hoist into loop
}

// generic GEMM with per-z offsets: C = A*Bt^T + bias [+Rsd][ReLU]
template<bool RELU, bool RESID, bool OUTF32>
__global__ __launch_bounds__(256) void k_gemm(
    const u16* __restrict__ A, int lda, long aZ,
    const u16* __restrict__ Bt, long bZ,
    const float* __restrict__ bias, long biasZ,
    const u16* __restrict__ Rsd, int ldr, long rZ,
    void* __restrict__ Cp, int ldc, long cZ, int K)
{
  int bx, by, bz; remap(bx, by, bz);
  A += (long)bz * aZ; Bt += (long)bz * bZ; bias += (long)bz * biasZ;
  __shared__ alignas(16) u16 As[3 * 4096];
  __shared__ alignas(16) u16 Bs[3 * 4096];
  f32x4 acc[4][4] = {};
  gemm_cv(A, lda, Bt, K, As, Bs, acc, bx, by);
  const int ln = threadIdx.x & 63;
  const int w = threadIdx.x >> 6;
  const int wm = w >> 1, wn = w & 1;
  const int m0 = bx * 128, n0 = by * 128;
#pragma unroll
  for (int n = 0; n < 4; ++n) {
    const int gc = n0 + wn * 64 + n * 16 + (ln & 15);
    const float bv = bias[gc];
#pragma unroll
    for (int m = 0; m < 4; ++m) {
#pragma unroll
      for (int j = 0; j < 4; ++j) {
        const int gr = m0 + wm * 64 + m * 16 + (ln >> 4) * 4 + j;
        float v = acc[m][n][j] + bv;
        if constexpr (RESID) v += bf2f(Rsd[(long)bz * rZ + (size_t)gr * ldr + gc]);
        if constexpr (RELU)  v = v > 0.f ? v : 0.f;
        if constexpr (OUTF32) ((float*)Cp)[(long)bz * cZ + (size_t)gr * ldc + gc] = v;
        else                  ((u16*)Cp)[(long)bz * cZ + (size_t)gr * ldc + gc] = f2bf(v);
      }
    }
  }
}

// K-projection GEMM with fused q.k dot epilogue, N-BATCHED over streams:
// z = kp only; B = [2048][512] = all 4 streams' WkT (contiguous per layer).
// A (x_kp) staged once per kp instead of once per (s,kp) -> 4x less A-fetch.
// Wave wn covers one 64-col head block: s = colbase>>9, h = (colbase>>6)&7.
// Writes raw scores (x1/8) to wbuf[s][b][h][kp]. K-bias softmax-invariant.
__global__ __launch_bounds__(256) void k_kdot(
    const u16* __restrict__ xcat, const u16* __restrict__ WkT_l,
    const u16* __restrict__ Qb, float* __restrict__ wbuf)
{
  int bx, by, kp; remap(bx, by, kp);
  __shared__ alignas(16) u16 As[3 * 4096];
  __shared__ alignas(16) u16 Bs[3 * 4096];
  f32x4 acc[4][4] = {};
  gemm_cv(xcat + kp * DM, XW, WkT_l, DM, As, Bs, acc, bx, by);
  const int ln = threadIdx.x & 63;
  const int w = threadIdx.x >> 6;
  const int wm = w >> 1, wn = w & 1;
  const int m0 = bx * 128, n0 = by * 128;
  const int colbase = n0 + wn * 64;
  const int s = colbase >> 9;
  const int h = (colbase >> 6) & 7;
  float p[4][4];
#pragma unroll
  for (int m = 0; m < 4; ++m)
#pragma unroll
    for (int j = 0; j < 4; ++j) p[m][j] = 0.f;
#pragma unroll
  for (int n = 0; n < 4; ++n) {
    const int qc = (colbase & 511) + n * 16 + (ln & 15);   // column within stream s
#pragma unroll
    for (int m = 0; m < 4; ++m) {
#pragma unroll
      for (int j = 0; j < 4; ++j) {
        const int gr = m0 + wm * 64 + m * 16 + (ln >> 4) * 4 + j;
        p[m][j] += acc[m][n][j] * bf2f(Qb[((size_t)s * NB + gr) * DM + qc]);
      }
    }
  }
#pragma unroll
  for (int m = 0; m < 4; ++m)
#pragma unroll
    for (int j = 0; j < 4; ++j) {
      float v = p[m][j];
      v += __shfl_xor(v, 1, 64);
      v += __shfl_xor(v, 2, 64);
      v += __shfl_xor(v, 4, 64);
      v += __shfl_xor(v, 8, 64);
      p[m][j] = v;
    }
  if ((ln & 15) == 0) {
#pragma unroll
    for (int m = 0; m < 4; ++m)
#pragma unroll
      for (int j = 0; j < 4; ++j) {
        const int gr = m0 + wm * 64 + m * 16 + (ln >> 4) * 4 + j;
        wbuf[(((size_t)s * NB + gr) * 8 + h) * 4 + kp] = p[m][j] * 0.125f;
      }
  }
}

// V-projection for all 4 key positions fused: facc = sum_kp w[s,b,h,kp]*((x_kp Wv)_gc + bv)
// single bf16 write of ctxc [B][2048]; softmax weights read between phases.
__global__ __launch_bounds__(256) void k_gemmv4(
    const u16* __restrict__ xcat, const u16* __restrict__ WvT_l,
    const float* __restrict__ bv_l, const float* __restrict__ wbuf,
    u16* __restrict__ ctxc)
{
  int bx, by, bz; remap(bx, by, bz); (void)bz;
  __shared__ alignas(16) u16 As[3 * 4096];
  __shared__ alignas(16) u16 Bs[3 * 4096];
  const int ln = threadIdx.x & 63;
  const int w = threadIdx.x >> 6;
  const int wm = w >> 1, wn = w & 1;
  const int m0 = bx * 128, n0 = by * 128;
  const int s  = n0 >> 9;
  const int hh = ((n0 >> 6) + wn) & 7;
  f32x4 facc[4][4] = {};
  for (int kp = 0; kp < 4; ++kp) {
    f32x4 acc[4][4] = {};
    gemm_cv(xcat + kp * DM, XW, WvT_l, DM, As, Bs, acc, bx, by);
    float wv[4][4];
#pragma unroll
    for (int m = 0; m < 4; ++m)
#pragma unroll
      for (int j = 0; j < 4; ++j) {
        const int gr = m0 + wm * 64 + m * 16 + (ln >> 4) * 4 + j;
        wv[m][j] = wbuf[(((size_t)s * NB + gr) * 8 + hh) * 4 + kp];
      }
#pragma unroll
    for (int n = 0; n < 4; ++n) {
      const float bvv = bv_l[n0 + wn * 64 + n * 16 + (ln & 15)];
#pragma unroll
      for (int m = 0; m < 4; ++m)
#pragma unroll
        for (int j = 0; j < 4; ++j)
          facc[m][n][j] += (acc[m][n][j] + bvv) * wv[m][j];
    }
  }
#pragma unroll
  for (int n = 0; n < 4; ++n) {
    const int gc = n0 + wn * 64 + n * 16 + (ln & 15);
#pragma unroll
    for (int m = 0; m < 4; ++m)
#pragma unroll
      for (int j = 0; j < 4; ++j) {
        const int gr = m0 + wm * 64 + m * 16 + (ln >> 4) * 4 + j;
        ctxc[(size_t)gr * XW + gc] = f2bf(facc[m][n][j]);
      }
  }
}

// softmax over kp in-place on wbuf [S][B][H][4]; optional write to attn0
__global__ __launch_bounds__(256) void k_softmax(
    float* __restrict__ wbuf, float* __restrict__ a0)
{
  const int t = blockIdx.x * 256 + threadIdx.x;   // (s*NB + b)*8 + h
  float4 v = ((const float4*)wbuf)[t];
  const float mx = fmaxf(fmaxf(v.x, v.y), fmaxf(v.z, v.w));
  float4 e;
  e.x = __expf(v.x - mx); e.y = __expf(v.y - mx);
  e.z = __expf(v.z - mx); e.w = __expf(v.w - mx);
  const float inv = 1.f / (e.x + e.y + e.z + e.w);
  e.x *= inv; e.y *= inv; e.z *= inv; e.w *= inv;
  ((float4*)wbuf)[t] = e;
  if (a0 != nullptr) {
    const int s = t >> 17, b = (t >> 3) & (NB - 1), h = t & 7;
    ((float4*)a0)[((size_t)b * NS + s) * 8 + h] = e;
  }
}

// in-place LayerNorm over each 512-wide stream block of xcat; wave per (b,s)
__global__ __launch_bounds__(256) void k_ln(
    u16* __restrict__ xcat, const float* __restrict__ g, const float* __restrict__ bb)
{
  const int ln = threadIdx.x & 63;
  const int row = blockIdx.x * 4 + (threadIdx.x >> 6);
  const int b = row >> 2, s = row & 3;
  u16* p = xcat + (size_t)b * XW + s * DM;
  float v[8];
  { uint4 t = ((const uint4*)p)[ln]; unpack8(t, v); }
  float sum = 0.f;
#pragma unroll
  for (int j = 0; j < 8; ++j) sum += v[j];
#pragma unroll
  for (int off = 1; off < 64; off <<= 1) sum += __shfl_xor(sum, off, 64);
  const float mu = sum * (1.f / DM);
  float s2 = 0.f;
#pragma unroll
  for (int j = 0; j < 8; ++j) { float d = v[j] - mu; s2 += d * d; }
#pragma unroll
  for (int off = 1; off < 64; off <<= 1) s2 += __shfl_xor(s2, off, 64);
  const float rs = rsqrtf(s2 * (1.f / DM) + EPSL);
  const int e0 = s * DM + ln * 8;
  float o[8];
#pragma unroll
  for (int j = 0; j < 8; ++j) o[j] = (v[j] - mu) * rs * g[e0 + j] + bb[e0 + j];
  ((uint4*)p)[ln] = pack8(o);
}

// pack 4 fp32 streams -> xcat bf16 [B][S*D]
__global__ void k_pack(const float* __restrict__ t0, const float* __restrict__ t1,
                       const float* __restrict__ t2, const float* __restrict__ t3,
                       u16* __restrict__ xcat)
{
  const int total = NB * XW / 8;
  for (int t = blockIdx.x * blockDim.x + threadIdx.x; t < total; t += gridDim.x * blockDim.x) {
    const int b = t >> 8;
    const int r = t & 255;
    const int s = r >> 6;
    const int d0 = (r & 63) * 8;
    const float* p = (s == 0) ? t0 : (s == 1) ? t1 : (s == 2) ? t2 : t3;
    float f[8];
#pragma unroll
    for (int j = 0; j < 8; ++j) f[j] = p[(size_t)b * DM + d0 + j];
    ((uint4*)xcat)[t] = pack8(f);
  }
}

// coalesced transpose + fp32->bf16 via LDS 32x32 tiles.
// grid (C/32, R/32, nb), block 256. src nb x [R][C] -> dst nb x [C][R].
__global__ __launch_bounds__(256) void k_tcvt(
    const float* __restrict__ src, u16* __restrict__ dst, int R, int C)
{
  __shared__ float tl[32][33];
  const int cx = blockIdx.x * 32, ry = blockIdx.y * 32;
  const size_t base = (size_t)blockIdx.z * R * C;
  const int lx = threadIdx.x & 31, ly = threadIdx.x >> 5;   // 8 rows per pass
#pragma unroll
  for (int i = 0; i < 32; i += 8)
    tl[ly + i][lx] = src[base + (size_t)(ry + ly + i) * C + cx + lx];
  __syncthreads();
#pragma unroll
  for (int i = 0; i < 32; i += 8)
    dst[base + (size_t)(cx + ly + i) * R + ry + lx] = f2bf(tl[lx][ly + i]);
}

extern "C" void kernel_launch(void* const* d_in, const int* in_sizes, int n_in,
                              void* d_out, int out_size, void* d_ws, size_t ws_size,
                              hipStream_t stream)
{
  (void)in_sizes; (void)n_in; (void)out_size;
  const float* t0  = (const float*)d_in[0];
  const float* t1  = (const float*)d_in[1];
  const float* t2  = (const float*)d_in[2];
  const float* t3  = (const float*)d_in[3];
  const float* Wq  = (const float*)d_in[4];
  const float* bq  = (const float*)d_in[5];
  const float* Wk  = (const float*)d_in[6];
  const float* Wv  = (const float*)d_in[8];
  const float* bv  = (const float*)d_in[9];
  const float* Wo  = (const float*)d_in[10];
  const float* bo  = (const float*)d_in[11];
  const float* lng = (const float*)d_in[12];
  const float* lnb = (const float*)d_in[13];
  const float* W1  = (const float*)d_in[14];
  const float* b1  = (const float*)d_in[15];
  const float* W2  = (const float*)d_in[16];
  const float* b2  = (const float*)d_in[17];
  const float* Wf1 = (const float*)d_in[18];
  const float* bf1 = (const float*)d_in[19];
  const float* Wf2 = (const float*)d_in[20];
  const float* bf2 = (const float*)d_in[21];

  size_t off = 0;
  char* ws = (char*)d_ws;
  auto take = [&](size_t n) { char* p = ws + off; off += (n + 255) & ~(size_t)255; return p; };
  u16* WqT  = (u16*)take(8ull * DM * DM * 2);        //  4 MiB
  u16* WkT  = (u16*)take(8ull * DM * DM * 2);        //  4
  u16* WvT  = (u16*)take(8ull * DM * DM * 2);        //  4
  u16* WoT  = (u16*)take(8ull * DM * DM * 2);        //  4
  u16* W1T  = (u16*)take(8ull * DM * FH * 2);        // 16
  u16* W2T  = (u16*)take(8ull * FH * DM * 2);        // 16
  u16* Wf1T = (u16*)take((size_t)XW * 1024 * 2);     //  4
  u16* Wf2T = (u16*)take((size_t)1024 * DM * 2);     //  1
  u16* xcat = (u16*)take((size_t)NB * XW * 2);       // 64
  char* U1  = take((size_t)NB * XW * 2);             // 64: Qb | ctxc | ffn1 | y1
  float* wbuf = (float*)take(4ull * NB * 8 * 4 * 4); //  8
  const size_t needed = off;                          // ~189 MiB

  u16* Qb   = (u16*)U1;   // [S][B][512]
  u16* ctxc = (u16*)U1;   // [B][2048]
  u16* ffn1 = (u16*)U1;   // [B][2048] per stream
  u16* y1   = (u16*)U1;   // [B][1024]
  float* attn0 = (float*)d_out + (size_t)NB * DM;

  if (needed > ws_size) return;  // diagnostic: clean fail instead of GPU fault

  // weight prep: fp32 -> bf16, transposed to [N][K] (coalesced LDS transpose)
  k_tcvt<<<dim3(16, 16, 8), dim3(256), 0, stream>>>(Wq, WqT, DM, DM);
  k_tcvt<<<dim3(16, 16, 8), dim3(256), 0, stream>>>(Wk, WkT, DM, DM);
  k_tcvt<<<dim3(16, 16, 8), dim3(256), 0, stream>>>(Wv, WvT, DM, DM);
  k_tcvt<<<dim3(16, 16, 8), dim3(256), 0, stream>>>(Wo, WoT, DM, DM);
  k_tcvt<<<dim3(64, 16, 8), dim3(256), 0, stream>>>(W1, W1T, DM, FH);
  k_tcvt<<<dim3(16, 64, 8), dim3(256), 0, stream>>>(W2, W2T, FH, DM);
  k_tcvt<<<dim3(32, 64, 1), dim3(256), 0, stream>>>(Wf1, Wf1T, XW, 1024);
  k_tcvt<<<dim3(16, 32, 1), dim3(256), 0, stream>>>(Wf2, Wf2T, 1024, DM);
  k_pack<<<dim3(2048), dim3(256), 0, stream>>>(t0, t1, t2, t3, xcat);

  const long WSQ = (long)DM * DM;
  for (int ly = 0; ly < 2; ++ly) {
    const u16* WqT_l = WqT + (size_t)ly * 4 * WSQ;
    const u16* WkT_l = WkT + (size_t)ly * 4 * WSQ;
    const u16* WvT_l = WvT + (size_t)ly * 4 * WSQ;
    const u16* WoT_l = WoT + (size_t)ly * 4 * WSQ;
    // Q projection, all streams in one launch (z = s)
    k_gemm<false, false, false><<<dim3(128, 4, 4), dim3(256), 0, stream>>>(
        xcat, XW, DM, WqT_l, WSQ, bq + (size_t)ly * XW, DM,
        nullptr, 0, 0, Qb, DM, (long)NB * DM, DM);
    // K projection + fused q.k dot: z = kp, N = 2048 (all 4 streams' Wk)
    k_kdot<<<dim3(128, 16, 4), dim3(256), 0, stream>>>(xcat, WkT_l, Qb, wbuf);
    k_softmax<<<dim3(4 * NB * 8 / 256), dim3(256), 0, stream>>>(
        wbuf, (ly == 0) ? attn0 : (float*)nullptr);
    // V projection (N=2048 over streams), all 4 kp fused, fp32 reg accumulate
    k_gemmv4<<<dim3(128, 16), dim3(256), 0, stream>>>(
        xcat, WvT_l, bv + (size_t)ly * XW, wbuf, ctxc);
    // O projection, residual-fused, in-place into xcat (z = s)
    k_gemm<false, true, false><<<dim3(128, 4, 4), dim3(256), 0, stream>>>(
        ctxc, XW, DM, WoT_l, WSQ, bo + (size_t)ly * XW, DM,
        xcat, XW, DM, xcat, XW, DM, DM);
    k_ln<<<dim3(NB), dim3(256), 0, stream>>>(xcat, lng + ly * XW, lnb + ly * XW);
    // FFN per stream, residual-fused, in-place into xcat
    for (int s = 0; s < NS; ++s) {
      const size_t wsl = (size_t)(ly * 4 + s);
      k_gemm<true, false, false><<<dim3(128, 16, 1), dim3(256), 0, stream>>>(
          xcat + s * DM, XW, 0, W1T + wsl * (size_t)DM * FH, 0, b1 + wsl * FH, 0,
          nullptr, 0, 0, ffn1, FH, 0, DM);
      k_gemm<false, true, false><<<dim3(128, 4, 1), dim3(256), 0, stream>>>(
          ffn1, FH, 0, W2T + wsl * (size_t)FH * DM, 0, b2 + wsl * DM, 0,
          xcat + s * DM, XW, 0, xcat + s * DM, XW, 0, FH);
    }
  }
  // final fusion MLP
  k_gemm<true, false, false><<<dim3(128, 8, 1), dim3(256), 0, stream>>>(
      xcat, XW, 0, Wf1T, 0, bf1, 0, nullptr, 0, 0, y1, 1024, 0, XW);
  k_gemm<false, false, true><<<dim3(128, 4, 1), dim3(256), 0, stream>>>(
      y1, 1024, 0, Wf2T, 0, bf2, 0, nullptr, 0, 0, d_out, DM, 0, 1024);
}

// Round 11
// 2249.129 us; speedup vs baseline: 1.8130x; 1.0872x over previous
//
#include <hip/hip_runtime.h>
#include <stdint.h>

typedef unsigned short u16;
typedef __bf16 bf16x8 __attribute__((ext_vector_type(8)));
typedef float f32x4 __attribute__((ext_vector_type(4)));

constexpr int NB = 16384;        // batch tokens
constexpr int DM = 512;          // model dim
constexpr int NS = 4;            // streams
constexpr int FH = 2048;         // FFN hidden
constexpr int XW = NS * DM;      // 2048 concat width
constexpr float EPSL = 1e-5f;

__device__ __forceinline__ float bf2f(u16 u) { return __uint_as_float(((uint32_t)u) << 16); }
__device__ __forceinline__ u16 f2bf(float f) {
  uint32_t u = __float_as_uint(f);
  u += 0x7fffu + ((u >> 16) & 1u);
  return (u16)(u >> 16);
}
__device__ __forceinline__ void unpack8(uint4 p, float* f) {
  f[0] = __uint_as_float(p.x << 16); f[1] = __uint_as_float(p.x & 0xffff0000u);
  f[2] = __uint_as_float(p.y << 16); f[3] = __uint_as_float(p.y & 0xffff0000u);
  f[4] = __uint_as_float(p.z << 16); f[5] = __uint_as_float(p.z & 0xffff0000u);
  f[6] = __uint_as_float(p.w << 16); f[7] = __uint_as_float(p.w & 0xffff0000u);
}
__device__ __forceinline__ uint4 pack8(const float* f) {
  uint4 r;
  r.x = (uint32_t)f2bf(f[0]) | ((uint32_t)f2bf(f[1]) << 16);
  r.y = (uint32_t)f2bf(f[2]) | ((uint32_t)f2bf(f[3]) << 16);
  r.z = (uint32_t)f2bf(f[4]) | ((uint32_t)f2bf(f[5]) << 16);
  r.w = (uint32_t)f2bf(f[6]) | ((uint32_t)f2bf(f[7]) << 16);
  return r;
}
__device__ __forceinline__ uint32_t cvtpk(float lo, float hi) {
  uint32_t d;
  asm("v_cvt_pk_bf16_f32 %0, %1, %2" : "=v"(d) : "v"(lo), "v"(hi));
  return d;
}
__device__ __forceinline__ void gl_lds16(const void* g, void* l) {
  __builtin_amdgcn_global_load_lds((const __attribute__((address_space(1))) void*)g,
                                   (__attribute__((address_space(3))) void*)l, 16, 0, 0);
}

// XCD-aware bijective remap. gx%8==0 required (all launches satisfy).
__device__ __forceinline__ void remap(int& bx, int& by, int& bz) {
  const int gx = gridDim.x, gy = gridDim.y;
  const int fl = (blockIdx.z * gy + blockIdx.y) * gx + blockIdx.x;
  const int xcd = fl & 7;
  const int t = fl >> 3;
  const int bw = gx >> 3;
  bx = xcd * bw + t % bw;
  const int u = t / bw;
  by = u % gy;
  bz = u / gy;
}

// ---- counted-vmcnt 3-buffer GEMM core: 128x128 tile, BK=32, 256 threads ----
// (champion r5 core, byte-identical) LDS write-linear for global_load_lds;
// GLOBAL source 16B-block pre-permuted blk^=(row>>1)&3, reads apply the same
// XOR -> even bank spread (conflict-free). Pipeline: stage tile t+2 during
// compute of t; vmcnt(4) + raw s_barrier; loop body has no other vmem.
__device__ __forceinline__ void gemm_cv(
    const u16* __restrict__ A, int lda,
    const u16* __restrict__ Bt, int K,    // Bt row stride == K
    u16* As, u16* Bs, f32x4 (&acc)[4][4], int bx, int by)
{
  const int tid = threadIdx.x;
  const int ln = tid & 63;
  const int w  = tid >> 6;
  const int wm = w >> 1, wn = w & 1;
  const int m0 = bx * 128;
  const int n0 = by * 128;
  const int grow = ln >> 2;                                  // row within 16-chunk
  const int gcol = ((ln & 3) ^ ((ln >> 3) & 3)) * 8;         // swizzled src 16B-block
  const u16* Ab = A  + (size_t)(m0 + w * 32 + grow) * lda + gcol;
  const u16* Bb = Bt + (size_t)(n0 + w * 32 + grow) * K   + gcol;

  auto stage = [&](int buf, int k0) {
#pragma unroll
    for (int i = 0; i < 2; ++i) {
      gl_lds16(Ab + (size_t)i * 16 * lda + k0, &As[buf * 4096 + (w * 32 + i * 16) * 32]);
      gl_lds16(Bb + (size_t)i * 16 * K   + k0, &Bs[buf * 4096 + (w * 32 + i * 16) * 32]);
    }
  };

  __syncthreads();               // protect LDS reuse across successive calls
  const int nt = K >> 5;
  stage(0, 0);
  if (nt > 1) {
    stage(1, 32);
    asm volatile("s_waitcnt vmcnt(4)" ::: "memory");
  } else {
    asm volatile("s_waitcnt vmcnt(0)" ::: "memory");
  }
  __builtin_amdgcn_s_barrier();
  asm volatile("" ::: "memory");

  const int rx = ((ln & 15) >> 1) & 3;   // per-row read XOR
  const int qb = ln >> 4;
  const int cb = (qb ^ rx) * 8;          // swizzled read 16B-block (elems)
  int cur = 0, nxt2 = 2;
  for (int t = 0; t < nt; ++t) {
    bf16x8 af[4], bfv[4];
#pragma unroll
    for (int m = 0; m < 4; ++m) {
      af[m]  = *(const bf16x8*)&As[cur * 4096 + (wm * 64 + m * 16 + (ln & 15)) * 32 + cb];
      bfv[m] = *(const bf16x8*)&Bs[cur * 4096 + (wn * 64 + m * 16 + (ln & 15)) * 32 + cb];
    }
#pragma unroll
    for (int m = 0; m < 4; ++m)
#pragma unroll
      for (int n = 0; n < 4; ++n)
        acc[m][n] = __builtin_amdgcn_mfma_f32_16x16x32_bf16(af[m], bfv[n], acc[m][n], 0, 0, 0);
    if (t + 2 < nt) {
      stage(nxt2, (t + 2) * 32);
      asm volatile("s_waitcnt vmcnt(4)" ::: "memory");   // tile t+1 ready, t+2 in flight
      __builtin_amdgcn_s_barrier();
      asm volatile("" ::: "memory");
    } else if (t + 1 < nt) {
      asm volatile("s_waitcnt vmcnt(0)" ::: "memory");   // drain last tile
      __builtin_amdgcn_s_barrier();
      asm volatile("" ::: "memory");
    }
    cur = cur + 1;  if (cur == 3)  cur = 0;
    nxt2 = nxt2 + 1; if (nxt2 == 3) nxt2 = 0;
  }
  asm volatile("" ::: "memory");   // fence: epilogue vmem must not hoist into loop
}

// generic GEMM with per-z offsets: C = A*Bt^T + bias [+Rsd][ReLU]
template<bool RELU, bool RESID, bool OUTF32>
__global__ __launch_bounds__(256) void k_gemm(
    const u16* __restrict__ A, int lda, long aZ,
    const u16* __restrict__ Bt, long bZ,
    const float* __restrict__ bias, long biasZ,
    const u16* __restrict__ Rsd, int ldr, long rZ,
    void* __restrict__ Cp, int ldc, long cZ, int K)
{
  int bx, by, bz; remap(bx, by, bz);
  A += (long)bz * aZ; Bt += (long)bz * bZ; bias += (long)bz * biasZ;
  __shared__ alignas(16) u16 As[3 * 4096];
  __shared__ alignas(16) u16 Bs[3 * 4096];
  f32x4 acc[4][4] = {};
  gemm_cv(A, lda, Bt, K, As, Bs, acc, bx, by);
  const int ln = threadIdx.x & 63;
  const int w = threadIdx.x >> 6;
  const int wm = w >> 1, wn = w & 1;
  const int m0 = bx * 128, n0 = by * 128;
#pragma unroll
  for (int n = 0; n < 4; ++n) {
    const int gc = n0 + wn * 64 + n * 16 + (ln & 15);
    const float bv = bias[gc];
#pragma unroll
    for (int m = 0; m < 4; ++m) {
#pragma unroll
      for (int j = 0; j < 4; ++j) {
        const int gr = m0 + wm * 64 + m * 16 + (ln >> 4) * 4 + j;
        float v = acc[m][n][j] + bv;
        if constexpr (RESID) v += bf2f(Rsd[(long)bz * rZ + (size_t)gr * ldr + gc]);
        if constexpr (RELU)  v = v > 0.f ? v : 0.f;
        if constexpr (OUTF32) ((float*)Cp)[(long)bz * cZ + (size_t)gr * ldc + gc] = v;
        else                  ((u16*)Cp)[(long)bz * cZ + (size_t)gr * ldc + gc] = f2bf(v);
      }
    }
  }
}

// K-projection GEMM with fused q.k dot epilogue, N-BATCHED over streams:
// z = kp only; B = [2048][512] = all 4 streams' WkT (contiguous per layer).
// Writes raw scores (x1/8) to wbuf[s][b][h][kp]. K-bias softmax-invariant.
__global__ __launch_bounds__(256) void k_kdot(
    const u16* __restrict__ xcat, const u16* __restrict__ WkT_l,
    const u16* __restrict__ Qb, float* __restrict__ wbuf)
{
  int bx, by, kp; remap(bx, by, kp);
  __shared__ alignas(16) u16 As[3 * 4096];
  __shared__ alignas(16) u16 Bs[3 * 4096];
  f32x4 acc[4][4] = {};
  gemm_cv(xcat + kp * DM, XW, WkT_l, DM, As, Bs, acc, bx, by);
  const int ln = threadIdx.x & 63;
  const int w = threadIdx.x >> 6;
  const int wm = w >> 1, wn = w & 1;
  const int m0 = bx * 128, n0 = by * 128;
  const int colbase = n0 + wn * 64;
  const int s = colbase >> 9;
  const int h = (colbase >> 6) & 7;
  float p[4][4];
#pragma unroll
  for (int m = 0; m < 4; ++m)
#pragma unroll
    for (int j = 0; j < 4; ++j) p[m][j] = 0.f;
#pragma unroll
  for (int n = 0; n < 4; ++n) {
    const int qc = (colbase & 511) + n * 16 + (ln & 15);   // column within stream s
#pragma unroll
    for (int m = 0; m < 4; ++m) {
#pragma unroll
      for (int j = 0; j < 4; ++j) {
        const int gr = m0 + wm * 64 + m * 16 + (ln >> 4) * 4 + j;
        p[m][j] += acc[m][n][j] * bf2f(Qb[((size_t)s * NB + gr) * DM + qc]);
      }
    }
  }
#pragma unroll
  for (int m = 0; m < 4; ++m)
#pragma unroll
    for (int j = 0; j < 4; ++j) {
      float v = p[m][j];
      v += __shfl_xor(v, 1, 64);
      v += __shfl_xor(v, 2, 64);
      v += __shfl_xor(v, 4, 64);
      v += __shfl_xor(v, 8, 64);
      p[m][j] = v;
    }
  if ((ln & 15) == 0) {
#pragma unroll
    for (int m = 0; m < 4; ++m)
#pragma unroll
      for (int j = 0; j < 4; ++j) {
        const int gr = m0 + wm * 64 + m * 16 + (ln >> 4) * 4 + j;
        wbuf[(((size_t)s * NB + gr) * 8 + h) * 4 + kp] = p[m][j] * 0.125f;
      }
  }
}

// V-projection via PRE-MIXED A (FLOP cut 4x): ctx[b, s*512+c] =
// (sum_kp w[s,b,h(c),kp] x_kp[b,:]) . Wv[s][:,c] + bv   (valid since sum w = 1)
// Block: 128 b-rows x 128 cols = 2 heads; wave wn's 64 cols = ONE head.
// Per K-step: reg-load 4 kp A-chunks (T14 issue-early), mix in f32 with
// per-row float4 weights, cvt_pk to bf16, ds_write frag-major (2 mixed tiles);
// B via global_load_lds frag-major. One ds-pipelined K=512 GEMM, 16 steps.
__global__ __launch_bounds__(256) void k_gemmvm(
    const u16* __restrict__ xcat, const u16* __restrict__ WvT_l,
    const float* __restrict__ bv_l, const float* __restrict__ wbuf,
    u16* __restrict__ ctxc)
{
  int bx, by, bz; remap(bx, by, bz); (void)bz;
  __shared__ alignas(16) u16 Am[2 * 8192];   // [buf][head j][frag f][512]
  __shared__ alignas(16) u16 Bsh[2 * 4096];  // [buf][frag f][512]
  const int tid = threadIdx.x;
  const int ln = tid & 63;
  const int w  = tid >> 6;
  const int wm = w >> 1, wn = w & 1;
  const int m0 = bx * 128;
  const int n0 = by * 128;
  const int s  = n0 >> 9;
  const int h0 = (n0 >> 6) & 7;          // even head index of this block
  const int lr = ln & 15;
  const int kq = (ln >> 4) * 8;          // k sub-offset within 32-chunk
  const u16* Abase = xcat  + (size_t)(m0 + w * 32 + lr) * XW + kq;
  const u16* Bbase = WvT_l + (size_t)(n0 + w * 32 + lr) * DM + kq;

  // per-thread mix weights: rows r_i = m0 + (w*2+i)*16 + lr, heads h0+j
  float4 wg[2][2];
#pragma unroll
  for (int i = 0; i < 2; ++i) {
    const int r = m0 + (w * 2 + i) * 16 + lr;
#pragma unroll
    for (int j = 0; j < 2; ++j)
      wg[i][j] = *(const float4*)&wbuf[(((size_t)s * NB + r) * 8 + h0 + j) * 4];
  }

  uint4 ar[2][4];   // [i][kp] raw x chunks
  auto loadA = [&](int k0) {
#pragma unroll
    for (int i = 0; i < 2; ++i)
#pragma unroll
      for (int kp = 0; kp < 4; ++kp)
        ar[i][kp] = *(const uint4*)(Abase + (size_t)i * 16 * XW + kp * DM + k0);
  };
  auto loadB = [&](int buf, int k0) {
#pragma unroll
    for (int i = 0; i < 2; ++i)
      gl_lds16(Bbase + (size_t)i * 16 * DM + k0,
               &Bsh[buf * 4096 + (w * 2 + i) * 512 + ln * 8]);
  };
  auto mixwrite = [&](int buf) {
#pragma unroll
    for (int i = 0; i < 2; ++i) {
      float x[4][8];
#pragma unroll
      for (int kp = 0; kp < 4; ++kp) unpack8(ar[i][kp], x[kp]);
#pragma unroll
      for (int j = 0; j < 2; ++j) {
        const float4 g = wg[i][j];
        float o[8];
#pragma unroll
        for (int e = 0; e < 8; ++e)
          o[e] = g.x * x[0][e] + g.y * x[1][e] + g.z * x[2][e] + g.w * x[3][e];
        uint4 pk;
        pk.x = cvtpk(o[0], o[1]); pk.y = cvtpk(o[2], o[3]);
        pk.z = cvtpk(o[4], o[5]); pk.w = cvtpk(o[6], o[7]);
        *(uint4*)&Am[buf * 8192 + ((j * 8) + (w * 2 + i)) * 512 + ln * 8] = pk;
      }
    }
  };

  f32x4 acc[4][4] = {};
  const int nt = DM / 32;   // 16

  loadA(0); loadB(0, 0);
  asm volatile("s_waitcnt vmcnt(0)" ::: "memory");
  mixwrite(0);
  asm volatile("s_waitcnt lgkmcnt(0)" ::: "memory");
  __builtin_amdgcn_s_barrier();
  asm volatile("" ::: "memory");

  int cbuf = 0;
  for (int t = 0; t < nt; ++t) {
    if (t + 1 < nt) { loadA((t + 1) * 32); loadB(cbuf ^ 1, (t + 1) * 32); }
    bf16x8 af[4], bfv[4];
#pragma unroll
    for (int m = 0; m < 4; ++m)
      af[m] = *(const bf16x8*)&Am[cbuf * 8192 + (wn * 8 + wm * 4 + m) * 512 + ln * 8];
#pragma unroll
    for (int n = 0; n < 4; ++n)
      bfv[n] = *(const bf16x8*)&Bsh[cbuf * 4096 + (wn * 4 + n) * 512 + ln * 8];
#pragma unroll
    for (int m = 0; m < 4; ++m)
#pragma unroll
      for (int n = 0; n < 4; ++n)
        acc[m][n] = __builtin_amdgcn_mfma_f32_16x16x32_bf16(af[m], bfv[n], acc[m][n], 0, 0, 0);
    if (t + 1 < nt) {
      asm volatile("s_waitcnt vmcnt(0)" ::: "memory");   // A regs + B lds landed
      mixwrite(cbuf ^ 1);
      asm volatile("s_waitcnt lgkmcnt(0)" ::: "memory"); // ds_writes visible
      __builtin_amdgcn_s_barrier();
      asm volatile("" ::: "memory");
      cbuf ^= 1;
    }
  }

  // epilogue: + bias, bf16 store (fragment C/D layout proven r6/r10)
#pragma unroll
  for (int nf = 0; nf < 4; ++nf) {
    const int gc = n0 + wn * 64 + nf * 16 + (ln & 15);
    const float bvv = bv_l[gc];
#pragma unroll
    for (int mf = 0; mf < 4; ++mf) {
#pragma unroll
      for (int j = 0; j < 4; ++j) {
        const int gr = m0 + wm * 64 + mf * 16 + (ln >> 4) * 4 + j;
        ctxc[(size_t)gr * XW + gc] = f2bf(acc[mf][nf][j] + bvv);
      }
    }
  }
}

// softmax over kp in-place on wbuf [S][B][H][4]; optional write to attn0
__global__ __launch_bounds__(256) void k_softmax(
    float* __restrict__ wbuf, float* __restrict__ a0)
{
  const int t = blockIdx.x * 256 + threadIdx.x;   // (s*NB + b)*8 + h
  float4 v = ((const float4*)wbuf)[t];
  const float mx = fmaxf(fmaxf(v.x, v.y), fmaxf(v.z, v.w));
  float4 e;
  e.x = __expf(v.x - mx); e.y = __expf(v.y - mx);
  e.z = __expf(v.z - mx); e.w = __expf(v.w - mx);
  const float inv = 1.f / (e.x + e.y + e.z + e.w);
  e.x *= inv; e.y *= inv; e.z *= inv; e.w *= inv;
  ((float4*)wbuf)[t] = e;
  if (a0 != nullptr) {
    const int s = t >> 17, b = (t >> 3) & (NB - 1), h = t & 7;
    ((float4*)a0)[((size_t)b * NS + s) * 8 + h] = e;
  }
}

// in-place LayerNorm over each 512-wide stream block of xcat; wave per (b,s)
__global__ __launch_bounds__(256) void k_ln(
    u16* __restrict__ xcat, const float* __restrict__ g, const float* __restrict__ bb)
{
  const int ln = threadIdx.x & 63;
  const int row = blockIdx.x * 4 + (threadIdx.x >> 6);
  const int b = row >> 2, s = row & 3;
  u16* p = xcat + (size_t)b * XW + s * DM;
  float v[8];
  { uint4 t = ((const uint4*)p)[ln]; unpack8(t, v); }
  float sum = 0.f;
#pragma unroll
  for (int j = 0; j < 8; ++j) sum += v[j];
#pragma unroll
  for (int off = 1; off < 64; off <<= 1) sum += __shfl_xor(sum, off, 64);
  const float mu = sum * (1.f / DM);
  float s2 = 0.f;
#pragma unroll
  for (int j = 0; j < 8; ++j) { float d = v[j] - mu; s2 += d * d; }
#pragma unroll
  for (int off = 1; off < 64; off <<= 1) s2 += __shfl_xor(s2, off, 64);
  const float rs = rsqrtf(s2 * (1.f / DM) + EPSL);
  const int e0 = s * DM + ln * 8;
  float o[8];
#pragma unroll
  for (int j = 0; j < 8; ++j) o[j] = (v[j] - mu) * rs * g[e0 + j] + bb[e0 + j];
  ((uint4*)p)[ln] = pack8(o);
}

// pack 4 fp32 streams -> xcat bf16 [B][S*D]
__global__ void k_pack(const float* __restrict__ t0, const float* __restrict__ t1,
                       const float* __restrict__ t2, const float* __restrict__ t3,
                       u16* __restrict__ xcat)
{
  const int total = NB * XW / 8;
  for (int t = blockIdx.x * blockDim.x + threadIdx.x; t < total; t += gridDim.x * blockDim.x) {
    const int b = t >> 8;
    const int r = t & 255;
    const int s = r >> 6;
    const int d0 = (r & 63) * 8;
    const float* p = (s == 0) ? t0 : (s == 1) ? t1 : (s == 2) ? t2 : t3;
    float f[8];
#pragma unroll
    for (int j = 0; j < 8; ++j) f[j] = p[(size_t)b * DM + d0 + j];
    ((uint4*)xcat)[t] = pack8(f);
  }
}

// coalesced transpose + fp32->bf16 via LDS 32x32 tiles.
// grid (C/32, R/32, nb), block 256. src nb x [R][C] -> dst nb x [C][R].
__global__ __launch_bounds__(256) void k_tcvt(
    const float* __restrict__ src, u16* __restrict__ dst, int R, int C)
{
  __shared__ float tl[32][33];
  const int cx = blockIdx.x * 32, ry = blockIdx.y * 32;
  const size_t base = (size_t)blockIdx.z * R * C;
  const int lx = threadIdx.x & 31, ly = threadIdx.x >> 5;   // 8 rows per pass
#pragma unroll
  for (int i = 0; i < 32; i += 8)
    tl[ly + i][lx] = src[base + (size_t)(ry + ly + i) * C + cx + lx];
  __syncthreads();
#pragma unroll
  for (int i = 0; i < 32; i += 8)
    dst[base + (size_t)(cx + ly + i) * R + ry + lx] = f2bf(tl[lx][ly + i]);
}

extern "C" void kernel_launch(void* const* d_in, const int* in_sizes, int n_in,
                              void* d_out, int out_size, void* d_ws, size_t ws_size,
                              hipStream_t stream)
{
  (void)in_sizes; (void)n_in; (void)out_size;
  const float* t0  = (const float*)d_in[0];
  const float* t1  = (const float*)d_in[1];
  const float* t2  = (const float*)d_in[2];
  const float* t3  = (const float*)d_in[3];
  const float* Wq  = (const float*)d_in[4];
  const float* bq  = (const float*)d_in[5];
  const float* Wk  = (const float*)d_in[6];
  const float* Wv  = (const float*)d_in[8];
  const float* bv  = (const float*)d_in[9];
  const float* Wo  = (const float*)d_in[10];
  const float* bo  = (const float*)d_in[11];
  const float* lng = (const float*)d_in[12];
  const float* lnb = (const float*)d_in[13];
  const float* W1  = (const float*)d_in[14];
  const float* b1  = (const float*)d_in[15];
  const float* W2  = (const float*)d_in[16];
  const float* b2  = (const float*)d_in[17];
  const float* Wf1 = (const float*)d_in[18];
  const float* bf1 = (const float*)d_in[19];
  const float* Wf2 = (const float*)d_in[20];
  const float* bf2 = (const float*)d_in[21];

  size_t off = 0;
  char* ws = (char*)d_ws;
  auto take = [&](size_t n) { char* p = ws + off; off += (n + 255) & ~(size_t)255; return p; };
  u16* WqT  = (u16*)take(8ull * DM * DM * 2);        //  4 MiB
  u16* WkT  = (u16*)take(8ull * DM * DM * 2);        //  4
  u16* WvT  = (u16*)take(8ull * DM * DM * 2);        //  4
  u16* WoT  = (u16*)take(8ull * DM * DM * 2);        //  4
  u16* W1T  = (u16*)take(8ull * DM * FH * 2);        // 16
  u16* W2T  = (u16*)take(8ull * FH * DM * 2);        // 16
  u16* Wf1T = (u16*)take((size_t)XW * 1024 * 2);     //  4
  u16* Wf2T = (u16*)take((size_t)1024 * DM * 2);     //  1
  u16* xcat = (u16*)take((size_t)NB * XW * 2);       // 64
  char* U1  = take((size_t)NB * XW * 2);             // 64: Qb | ctxc | ffn1 | y1
  float* wbuf = (float*)take(4ull * NB * 8 * 4 * 4); //  8
  const size_t needed = off;                          // ~189 MiB

  u16* Qb   = (u16*)U1;   // [S][B][512]
  u16* ctxc = (u16*)U1;   // [B][2048]
  u16* ffn1 = (u16*)U1;   // [B][2048] per stream
  u16* y1   = (u16*)U1;   // [B][1024]
  float* attn0 = (float*)d_out + (size_t)NB * DM;

  if (needed > ws_size) return;  // diagnostic: clean fail instead of GPU fault

  // weight prep: fp32 -> bf16, transposed to [N][K] (coalesced LDS transpose)
  k_tcvt<<<dim3(16, 16, 8), dim3(256), 0, stream>>>(Wq, WqT, DM, DM);
  k_tcvt<<<dim3(16, 16, 8), dim3(256), 0, stream>>>(Wk, WkT, DM, DM);
  k_tcvt<<<dim3(16, 16, 8), dim3(256), 0, stream>>>(Wv, WvT, DM, DM);
  k_tcvt<<<dim3(16, 16, 8), dim3(256), 0, stream>>>(Wo, WoT, DM, DM);
  k_tcvt<<<dim3(64, 16, 8), dim3(256), 0, stream>>>(W1, W1T, DM, FH);
  k_tcvt<<<dim3(16, 64, 8), dim3(256), 0, stream>>>(W2, W2T, FH, DM);
  k_tcvt<<<dim3(32, 64, 1), dim3(256), 0, stream>>>(Wf1, Wf1T, XW, 1024);
  k_tcvt<<<dim3(16, 32, 1), dim3(256), 0, stream>>>(Wf2, Wf2T, 1024, DM);
  k_pack<<<dim3(2048), dim3(256), 0, stream>>>(t0, t1, t2, t3, xcat);

  const long WSQ = (long)DM * DM;
  for (int ly = 0; ly < 2; ++ly) {
    const u16* WqT_l = WqT + (size_t)ly * 4 * WSQ;
    const u16* WkT_l = WkT + (size_t)ly * 4 * WSQ;
    const u16* WvT_l = WvT + (size_t)ly * 4 * WSQ;
    const u16* WoT_l = WoT + (size_t)ly * 4 * WSQ;
    // Q projection, all streams in one launch (z = s)
    k_gemm<false, false, false><<<dim3(128, 4, 4), dim3(256), 0, stream>>>(
        xcat, XW, DM, WqT_l, WSQ, bq + (size_t)ly * XW, DM,
        nullptr, 0, 0, Qb, DM, (long)NB * DM, DM);
    // K projection + fused q.k dot: z = kp, N = 2048 (all 4 streams' Wk)
    k_kdot<<<dim3(128, 16, 4), dim3(256), 0, stream>>>(xcat, WkT_l, Qb, wbuf);
    k_softmax<<<dim3(4 * NB * 8 / 256), dim3(256), 0, stream>>>(
        wbuf, (ly == 0) ? attn0 : (float*)nullptr);
    // V projection via pre-mixed A (4x fewer FLOPs), one K=512 GEMM
    k_gemmvm<<<dim3(128, 16), dim3(256), 0, stream>>>(
        xcat, WvT_l, bv + (size_t)ly * XW, wbuf, ctxc);
    // O projection, residual-fused, in-place into xcat (z = s)
    k_gemm<false, true, false><<<dim3(128, 4, 4), dim3(256), 0, stream>>>(
        ctxc, XW, DM, WoT_l, WSQ, bo + (size_t)ly * XW, DM,
        xcat, XW, DM, xcat, XW, DM, DM);
    k_ln<<<dim3(NB), dim3(256), 0, stream>>>(xcat, lng + ly * XW, lnb + ly * XW);
    // FFN per stream, residual-fused, in-place into xcat
    for (int s = 0; s < NS; ++s) {
      const size_t wsl = (size_t)(ly * 4 + s);
      k_gemm<true, false, false><<<dim3(128, 16, 1), dim3(256), 0, stream>>>(
          xcat + s * DM, XW, 0, W1T + wsl * (size_t)DM * FH, 0, b1 + wsl * FH, 0,
          nullptr, 0, 0, ffn1, FH, 0, DM);
      k_gemm<false, true, false><<<dim3(128, 4, 1), dim3(256), 0, stream>>>(
          ffn1, FH, 0, W2T + wsl * (size_t)FH * DM, 0, b2 + wsl * DM, 0,
          xcat + s * DM, XW, 0, xcat + s * DM, XW, 0, FH);
    }
  }
  // final fusion MLP
  k_gemm<true, false, false><<<dim3(128, 8, 1), dim3(256), 0, stream>>>(
      xcat, XW, 0, Wf1T, 0, bf1, 0, nullptr, 0, 0, y1, 1024, 0, XW);
  k_gemm<false, false, true><<<dim3(128, 4, 1), dim3(256), 0, stream>>>(
      y1, 1024, 0, Wf2T, 0, bf2, 0, nullptr, 0, 0, d_out, DM, 0, 1024);
}

// Round 12
// 2233.085 us; speedup vs baseline: 1.8260x; 1.0072x over previous
//
#include <hip/hip_runtime.h>
#include <stdint.h>

typedef unsigned short u16;
typedef __bf16 bf16x8 __attribute__((ext_vector_type(8)));
typedef float f32x4 __attribute__((ext_vector_type(4)));

constexpr int NB = 16384;        // batch tokens
constexpr int DM = 512;          // model dim
constexpr int NS = 4;            // streams
constexpr int FH = 2048;         // FFN hidden
constexpr int XW = NS * DM;      // 2048 concat width
constexpr float EPSL = 1e-5f;

__device__ __forceinline__ float bf2f(u16 u) { return __uint_as_float(((uint32_t)u) << 16); }
__device__ __forceinline__ u16 f2bf(float f) {
  uint32_t u = __float_as_uint(f);
  u += 0x7fffu + ((u >> 16) & 1u);
  return (u16)(u >> 16);
}
__device__ __forceinline__ void unpack8(uint4 p, float* f) {
  f[0] = __uint_as_float(p.x << 16); f[1] = __uint_as_float(p.x & 0xffff0000u);
  f[2] = __uint_as_float(p.y << 16); f[3] = __uint_as_float(p.y & 0xffff0000u);
  f[4] = __uint_as_float(p.z << 16); f[5] = __uint_as_float(p.z & 0xffff0000u);
  f[6] = __uint_as_float(p.w << 16); f[7] = __uint_as_float(p.w & 0xffff0000u);
}
__device__ __forceinline__ uint4 pack8(const float* f) {
  uint4 r;
  r.x = (uint32_t)f2bf(f[0]) | ((uint32_t)f2bf(f[1]) << 16);
  r.y = (uint32_t)f2bf(f[2]) | ((uint32_t)f2bf(f[3]) << 16);
  r.z = (uint32_t)f2bf(f[4]) | ((uint32_t)f2bf(f[5]) << 16);
  r.w = (uint32_t)f2bf(f[6]) | ((uint32_t)f2bf(f[7]) << 16);
  return r;
}
__device__ __forceinline__ uint32_t cvtpk(float lo, float hi) {
  uint32_t d;
  asm("v_cvt_pk_bf16_f32 %0, %1, %2" : "=v"(d) : "v"(lo), "v"(hi));
  return d;
}
__device__ __forceinline__ void gl_lds16(const void* g, void* l) {
  __builtin_amdgcn_global_load_lds((const __attribute__((address_space(1))) void*)g,
                                   (__attribute__((address_space(3))) void*)l, 16, 0, 0);
}

// XCD-aware bijective remap. gx%8==0 required (all launches satisfy).
__device__ __forceinline__ void remap(int& bx, int& by, int& bz) {
  const int gx = gridDim.x, gy = gridDim.y;
  const int fl = (blockIdx.z * gy + blockIdx.y) * gx + blockIdx.x;
  const int xcd = fl & 7;
  const int t = fl >> 3;
  const int bw = gx >> 3;
  bx = xcd * bw + t % bw;
  const int u = t / bw;
  by = u % gy;
  bz = u / gy;
}

// ---- counted-vmcnt 3-buffer GEMM core: 128x128 tile, BK=32, 256 threads ----
// (champion r5 core, byte-identical) LDS write-linear for global_load_lds;
// GLOBAL source 16B-block pre-permuted blk^=(row>>1)&3, reads apply the same
// XOR -> even bank spread (conflict-free). Pipeline: stage tile t+2 during
// compute of t; vmcnt(4) + raw s_barrier; loop body has no other vmem.
__device__ __forceinline__ void gemm_cv(
    const u16* __restrict__ A, int lda,
    const u16* __restrict__ Bt, int K,    // Bt row stride == K
    u16* As, u16* Bs, f32x4 (&acc)[4][4], int bx, int by)
{
  const int tid = threadIdx.x;
  const int ln = tid & 63;
  const int w  = tid >> 6;
  const int wm = w >> 1, wn = w & 1;
  const int m0 = bx * 128;
  const int n0 = by * 128;
  const int grow = ln >> 2;                                  // row within 16-chunk
  const int gcol = ((ln & 3) ^ ((ln >> 3) & 3)) * 8;         // swizzled src 16B-block
  const u16* Ab = A  + (size_t)(m0 + w * 32 + grow) * lda + gcol;
  const u16* Bb = Bt + (size_t)(n0 + w * 32 + grow) * K   + gcol;

  auto stage = [&](int buf, int k0) {
#pragma unroll
    for (int i = 0; i < 2; ++i) {
      gl_lds16(Ab + (size_t)i * 16 * lda + k0, &As[buf * 4096 + (w * 32 + i * 16) * 32]);
      gl_lds16(Bb + (size_t)i * 16 * K   + k0, &Bs[buf * 4096 + (w * 32 + i * 16) * 32]);
    }
  };

  __syncthreads();               // protect LDS reuse across successive calls
  const int nt = K >> 5;
  stage(0, 0);
  if (nt > 1) {
    stage(1, 32);
    asm volatile("s_waitcnt vmcnt(4)" ::: "memory");
  } else {
    asm volatile("s_waitcnt vmcnt(0)" ::: "memory");
  }
  __builtin_amdgcn_s_barrier();
  asm volatile("" ::: "memory");

  const int rx = ((ln & 15) >> 1) & 3;   // per-row read XOR
  const int qb = ln >> 4;
  const int cb = (qb ^ rx) * 8;          // swizzled read 16B-block (elems)
  int cur = 0, nxt2 = 2;
  for (int t = 0; t < nt; ++t) {
    bf16x8 af[4], bfv[4];
#pragma unroll
    for (int m = 0; m < 4; ++m) {
      af[m]  = *(const bf16x8*)&As[cur * 4096 + (wm * 64 + m * 16 + (ln & 15)) * 32 + cb];
      bfv[m] = *(const bf16x8*)&Bs[cur * 4096 + (wn * 64 + m * 16 + (ln & 15)) * 32 + cb];
    }
#pragma unroll
    for (int m = 0; m < 4; ++m)
#pragma unroll
      for (int n = 0; n < 4; ++n)
        acc[m][n] = __builtin_amdgcn_mfma_f32_16x16x32_bf16(af[m], bfv[n], acc[m][n], 0, 0, 0);
    if (t + 2 < nt) {
      stage(nxt2, (t + 2) * 32);
      asm volatile("s_waitcnt vmcnt(4)" ::: "memory");   // tile t+1 ready, t+2 in flight
      __builtin_amdgcn_s_barrier();
      asm volatile("" ::: "memory");
    } else if (t + 1 < nt) {
      asm volatile("s_waitcnt vmcnt(0)" ::: "memory");   // drain last tile
      __builtin_amdgcn_s_barrier();
      asm volatile("" ::: "memory");
    }
    cur = cur + 1;  if (cur == 3)  cur = 0;
    nxt2 = nxt2 + 1; if (nxt2 == 3) nxt2 = 0;
  }
  asm volatile("" ::: "memory");   // fence: epilogue vmem must not hoist into loop
}

// generic GEMM with per-z offsets: C = A*Bt^T + bias [+Rsd][ReLU]
template<bool RELU, bool RESID, bool OUTF32>
__global__ __launch_bounds__(256) void k_gemm(
    const u16* __restrict__ A, int lda, long aZ,
    const u16* __restrict__ Bt, long bZ,
    const float* __restrict__ bias, long biasZ,
    const u16* __restrict__ Rsd, int ldr, long rZ,
    void* __restrict__ Cp, int ldc, long cZ, int K)
{
  int bx, by, bz; remap(bx, by, bz);
  A += (long)bz * aZ; Bt += (long)bz * bZ; bias += (long)bz * biasZ;
  __shared__ alignas(16) u16 As[3 * 4096];
  __shared__ alignas(16) u16 Bs[3 * 4096];
  f32x4 acc[4][4] = {};
  gemm_cv(A, lda, Bt, K, As, Bs, acc, bx, by);
  const int ln = threadIdx.x & 63;
  const int w = threadIdx.x >> 6;
  const int wm = w >> 1, wn = w & 1;
  const int m0 = bx * 128, n0 = by * 128;
#pragma unroll
  for (int n = 0; n < 4; ++n) {
    const int gc = n0 + wn * 64 + n * 16 + (ln & 15);
    const float bv = bias[gc];
#pragma unroll
    for (int m = 0; m < 4; ++m) {
#pragma unroll
      for (int j = 0; j < 4; ++j) {
        const int gr = m0 + wm * 64 + m * 16 + (ln >> 4) * 4 + j;
        float v = acc[m][n][j] + bv;
        if constexpr (RESID) v += bf2f(Rsd[(long)bz * rZ + (size_t)gr * ldr + gc]);
        if constexpr (RELU)  v = v > 0.f ? v : 0.f;
        if constexpr (OUTF32) ((float*)Cp)[(long)bz * cZ + (size_t)gr * ldc + gc] = v;
        else                  ((u16*)Cp)[(long)bz * cZ + (size_t)gr * ldc + gc] = f2bf(v);
      }
    }
  }
}

// K-projection GEMM with fused q.k dot epilogue, N-BATCHED over streams:
// z = kp only; B = [2048][512] = all 4 streams' WkT (contiguous per layer).
// Writes raw scores (x1/8) to wbuf[s][b][h][kp]. K-bias softmax-invariant.
__global__ __launch_bounds__(256) void k_kdot(
    const u16* __restrict__ xcat, const u16* __restrict__ WkT_l,
    const u16* __restrict__ Qb, float* __restrict__ wbuf)
{
  int bx, by, kp; remap(bx, by, kp);
  __shared__ alignas(16) u16 As[3 * 4096];
  __shared__ alignas(16) u16 Bs[3 * 4096];
  f32x4 acc[4][4] = {};
  gemm_cv(xcat + kp * DM, XW, WkT_l, DM, As, Bs, acc, bx, by);
  const int ln = threadIdx.x & 63;
  const int w = threadIdx.x >> 6;
  const int wm = w >> 1, wn = w & 1;
  const int m0 = bx * 128, n0 = by * 128;
  const int colbase = n0 + wn * 64;
  const int s = colbase >> 9;
  const int h = (colbase >> 6) & 7;
  float p[4][4];
#pragma unroll
  for (int m = 0; m < 4; ++m)
#pragma unroll
    for (int j = 0; j < 4; ++j) p[m][j] = 0.f;
#pragma unroll
  for (int n = 0; n < 4; ++n) {
    const int qc = (colbase & 511) + n * 16 + (ln & 15);   // column within stream s
#pragma unroll
    for (int m = 0; m < 4; ++m) {
#pragma unroll
      for (int j = 0; j < 4; ++j) {
        const int gr = m0 + wm * 64 + m * 16 + (ln >> 4) * 4 + j;
        p[m][j] += acc[m][n][j] * bf2f(Qb[((size_t)s * NB + gr) * DM + qc]);
      }
    }
  }
#pragma unroll
  for (int m = 0; m < 4; ++m)
#pragma unroll
    for (int j = 0; j < 4; ++j) {
      float v = p[m][j];
      v += __shfl_xor(v, 1, 64);
      v += __shfl_xor(v, 2, 64);
      v += __shfl_xor(v, 4, 64);
      v += __shfl_xor(v, 8, 64);
      p[m][j] = v;
    }
  if ((ln & 15) == 0) {
#pragma unroll
    for (int m = 0; m < 4; ++m)
#pragma unroll
      for (int j = 0; j < 4; ++j) {
        const int gr = m0 + wm * 64 + m * 16 + (ln >> 4) * 4 + j;
        wbuf[(((size_t)s * NB + gr) * 8 + h) * 4 + kp] = p[m][j] * 0.125f;
      }
  }
}

// V-projection via PRE-MIXED A (FLOP cut 4x): ctx[b, s*512+c] =
// (sum_kp w[s,b,h(c),kp] x_kp[b,:]) . Wv[s][:,c] + bv   (valid since sum w = 1)
// Block: 128 b-rows x 128 cols = 2 heads; wave wn's 64 cols = ONE head.
__global__ __launch_bounds__(256) void k_gemmvm(
    const u16* __restrict__ xcat, const u16* __restrict__ WvT_l,
    const float* __restrict__ bv_l, const float* __restrict__ wbuf,
    u16* __restrict__ ctxc)
{
  int bx, by, bz; remap(bx, by, bz); (void)bz;
  __shared__ alignas(16) u16 Am[2 * 8192];   // [buf][head j][frag f][512]
  __shared__ alignas(16) u16 Bsh[2 * 4096];  // [buf][frag f][512]
  const int tid = threadIdx.x;
  const int ln = tid & 63;
  const int w  = tid >> 6;
  const int wm = w >> 1, wn = w & 1;
  const int m0 = bx * 128;
  const int n0 = by * 128;
  const int s  = n0 >> 9;
  const int h0 = (n0 >> 6) & 7;          // even head index of this block
  const int lr = ln & 15;
  const int kq = (ln >> 4) * 8;          // k sub-offset within 32-chunk
  const u16* Abase = xcat  + (size_t)(m0 + w * 32 + lr) * XW + kq;
  const u16* Bbase = WvT_l + (size_t)(n0 + w * 32 + lr) * DM + kq;

  // per-thread mix weights: rows r_i = m0 + (w*2+i)*16 + lr, heads h0+j
  float4 wg[2][2];
#pragma unroll
  for (int i = 0; i < 2; ++i) {
    const int r = m0 + (w * 2 + i) * 16 + lr;
#pragma unroll
    for (int j = 0; j < 2; ++j)
      wg[i][j] = *(const float4*)&wbuf[(((size_t)s * NB + r) * 8 + h0 + j) * 4];
  }

  uint4 ar[2][4];   // [i][kp] raw x chunks
  auto loadA = [&](int k0) {
#pragma unroll
    for (int i = 0; i < 2; ++i)
#pragma unroll
      for (int kp = 0; kp < 4; ++kp)
        ar[i][kp] = *(const uint4*)(Abase + (size_t)i * 16 * XW + kp * DM + k0);
  };
  auto loadB = [&](int buf, int k0) {
#pragma unroll
    for (int i = 0; i < 2; ++i)
      gl_lds16(Bbase + (size_t)i * 16 * DM + k0,
               &Bsh[buf * 4096 + (w * 2 + i) * 512 + ln * 8]);
  };
  auto mixwrite = [&](int buf) {
#pragma unroll
    for (int i = 0; i < 2; ++i) {
      float x[4][8];
#pragma unroll
      for (int kp = 0; kp < 4; ++kp) unpack8(ar[i][kp], x[kp]);
#pragma unroll
      for (int j = 0; j < 2; ++j) {
        const float4 g = wg[i][j];
        float o[8];
#pragma unroll
        for (int e = 0; e < 8; ++e)
          o[e] = g.x * x[0][e] + g.y * x[1][e] + g.z * x[2][e] + g.w * x[3][e];
        uint4 pk;
        pk.x = cvtpk(o[0], o[1]); pk.y = cvtpk(o[2], o[3]);
        pk.z = cvtpk(o[4], o[5]); pk.w = cvtpk(o[6], o[7]);
        *(uint4*)&Am[buf * 8192 + ((j * 8) + (w * 2 + i)) * 512 + ln * 8] = pk;
      }
    }
  };

  f32x4 acc[4][4] = {};
  const int nt = DM / 32;   // 16

  loadA(0); loadB(0, 0);
  asm volatile("s_waitcnt vmcnt(0)" ::: "memory");
  mixwrite(0);
  asm volatile("s_waitcnt lgkmcnt(0)" ::: "memory");
  __builtin_amdgcn_s_barrier();
  asm volatile("" ::: "memory");

  int cbuf = 0;
  for (int t = 0; t < nt; ++t) {
    if (t + 1 < nt) { loadA((t + 1) * 32); loadB(cbuf ^ 1, (t + 1) * 32); }
    bf16x8 af[4], bfv[4];
#pragma unroll
    for (int m = 0; m < 4; ++m)
      af[m] = *(const bf16x8*)&Am[cbuf * 8192 + (wn * 8 + wm * 4 + m) * 512 + ln * 8];
#pragma unroll
    for (int n = 0; n < 4; ++n)
      bfv[n] = *(const bf16x8*)&Bsh[cbuf * 4096 + (wn * 4 + n) * 512 + ln * 8];
#pragma unroll
    for (int m = 0; m < 4; ++m)
#pragma unroll
      for (int n = 0; n < 4; ++n)
        acc[m][n] = __builtin_amdgcn_mfma_f32_16x16x32_bf16(af[m], bfv[n], acc[m][n], 0, 0, 0);
    if (t + 1 < nt) {
      asm volatile("s_waitcnt vmcnt(0)" ::: "memory");   // A regs + B lds landed
      mixwrite(cbuf ^ 1);
      asm volatile("s_waitcnt lgkmcnt(0)" ::: "memory"); // ds_writes visible
      __builtin_amdgcn_s_barrier();
      asm volatile("" ::: "memory");
      cbuf ^= 1;
    }
  }

  // epilogue: + bias, bf16 store
#pragma unroll
  for (int nf = 0; nf < 4; ++nf) {
    const int gc = n0 + wn * 64 + nf * 16 + (ln & 15);
    const float bvv = bv_l[gc];
#pragma unroll
    for (int mf = 0; mf < 4; ++mf) {
#pragma unroll
      for (int j = 0; j < 4; ++j) {
        const int gr = m0 + wm * 64 + mf * 16 + (ln >> 4) * 4 + j;
        ctxc[(size_t)gr * XW + gc] = f2bf(acc[mf][nf][j] + bvv);
      }
    }
  }
}

// softmax over kp in-place on wbuf [S][B][H][4]; optional write to attn0
__global__ __launch_bounds__(256) void k_softmax(
    float* __restrict__ wbuf, float* __restrict__ a0)
{
  const int t = blockIdx.x * 256 + threadIdx.x;   // (s*NB + b)*8 + h
  float4 v = ((const float4*)wbuf)[t];
  const float mx = fmaxf(fmaxf(v.x, v.y), fmaxf(v.z, v.w));
  float4 e;
  e.x = __expf(v.x - mx); e.y = __expf(v.y - mx);
  e.z = __expf(v.z - mx); e.w = __expf(v.w - mx);
  const float inv = 1.f / (e.x + e.y + e.z + e.w);
  e.x *= inv; e.y *= inv; e.z *= inv; e.w *= inv;
  ((float4*)wbuf)[t] = e;
  if (a0 != nullptr) {
    const int s = t >> 17, b = (t >> 3) & (NB - 1), h = t & 7;
    ((float4*)a0)[((size_t)b * NS + s) * 8 + h] = e;
  }
}

// in-place LayerNorm over each 512-wide stream block of xcat; wave per (b,s)
__global__ __launch_bounds__(256) void k_ln(
    u16* __restrict__ xcat, const float* __restrict__ g, const float* __restrict__ bb)
{
  const int ln = threadIdx.x & 63;
  const int row = blockIdx.x * 4 + (threadIdx.x >> 6);
  const int b = row >> 2, s = row & 3;
  u16* p = xcat + (size_t)b * XW + s * DM;
  float v[8];
  { uint4 t = ((const uint4*)p)[ln]; unpack8(t, v); }
  float sum = 0.f;
#pragma unroll
  for (int j = 0; j < 8; ++j) sum += v[j];
#pragma unroll
  for (int off = 1; off < 64; off <<= 1) sum += __shfl_xor(sum, off, 64);
  const float mu = sum * (1.f / DM);
  float s2 = 0.f;
#pragma unroll
  for (int j = 0; j < 8; ++j) { float d = v[j] - mu; s2 += d * d; }
#pragma unroll
  for (int off = 1; off < 64; off <<= 1) s2 += __shfl_xor(s2, off, 64);
  const float rs = rsqrtf(s2 * (1.f / DM) + EPSL);
  const int e0 = s * DM + ln * 8;
  float o[8];
#pragma unroll
  for (int j = 0; j < 8; ++j) o[j] = (v[j] - mu) * rs * g[e0 + j] + bb[e0 + j];
  ((uint4*)p)[ln] = pack8(o);
}

// pack 4 fp32 streams -> xcat bf16 [B][S*D]
__global__ void k_pack(const float* __restrict__ t0, const float* __restrict__ t1,
                       const float* __restrict__ t2, const float* __restrict__ t3,
                       u16* __restrict__ xcat)
{
  const int total = NB * XW / 8;
  for (int t = blockIdx.x * blockDim.x + threadIdx.x; t < total; t += gridDim.x * blockDim.x) {
    const int b = t >> 8;
    const int r = t & 255;
    const int s = r >> 6;
    const int d0 = (r & 63) * 8;
    const float* p = (s == 0) ? t0 : (s == 1) ? t1 : (s == 2) ? t2 : t3;
    float f[8];
#pragma unroll
    for (int j = 0; j < 8; ++j) f[j] = p[(size_t)b * DM + d0 + j];
    ((uint4*)xcat)[t] = pack8(f);
  }
}

// coalesced transpose + fp32->bf16 via LDS 32x32 tiles.
__global__ __launch_bounds__(256) void k_tcvt(
    const float* __restrict__ src, u16* __restrict__ dst, int R, int C)
{
  __shared__ float tl[32][33];
  const int cx = blockIdx.x * 32, ry = blockIdx.y * 32;
  const size_t base = (size_t)blockIdx.z * R * C;
  const int lx = threadIdx.x & 31, ly = threadIdx.x >> 5;   // 8 rows per pass
#pragma unroll
  for (int i = 0; i < 32; i += 8)
    tl[ly + i][lx] = src[base + (size_t)(ry + ly + i) * C + cx + lx];
  __syncthreads();
#pragma unroll
  for (int i = 0; i < 32; i += 8)
    dst[base + (size_t)(cx + ly + i) * R + ry + lx] = f2bf(tl[lx][ly + i]);
}

extern "C" void kernel_launch(void* const* d_in, const int* in_sizes, int n_in,
                              void* d_out, int out_size, void* d_ws, size_t ws_size,
                              hipStream_t stream)
{
  (void)in_sizes; (void)n_in; (void)out_size;
  const float* t0  = (const float*)d_in[0];
  const float* t1  = (const float*)d_in[1];
  const float* t2  = (const float*)d_in[2];
  const float* t3  = (const float*)d_in[3];
  const float* Wq  = (const float*)d_in[4];
  const float* bq  = (const float*)d_in[5];
  const float* Wk  = (const float*)d_in[6];
  const float* Wv  = (const float*)d_in[8];
  const float* bv  = (const float*)d_in[9];
  const float* Wo  = (const float*)d_in[10];
  const float* bo  = (const float*)d_in[11];
  const float* lng = (const float*)d_in[12];
  const float* lnb = (const float*)d_in[13];
  const float* W1  = (const float*)d_in[14];
  const float* b1  = (const float*)d_in[15];
  const float* W2  = (const float*)d_in[16];
  const float* b2  = (const float*)d_in[17];
  const float* Wf1 = (const float*)d_in[18];
  const float* bf1 = (const float*)d_in[19];
  const float* Wf2 = (const float*)d_in[20];
  const float* bf2 = (const float*)d_in[21];

  size_t off = 0;
  char* ws = (char*)d_ws;
  auto take = [&](size_t n) { char* p = ws + off; off += (n + 255) & ~(size_t)255; return p; };
  u16* WqT  = (u16*)take(8ull * DM * DM * 2);        //  4 MiB
  u16* WkT  = (u16*)take(8ull * DM * DM * 2);        //  4
  u16* WvT  = (u16*)take(8ull * DM * DM * 2);        //  4
  u16* WoT  = (u16*)take(8ull * DM * DM * 2);        //  4
  u16* W1T  = (u16*)take(8ull * DM * FH * 2);        // 16
  u16* W2T  = (u16*)take(8ull * FH * DM * 2);        // 16
  u16* Wf1T = (u16*)take((size_t)XW * 1024 * 2);     //  4
  u16* Wf2T = (u16*)take((size_t)1024 * DM * 2);     //  1
  u16* xcat = (u16*)take((size_t)NB * XW * 2);       // 64
  char* U1  = take((size_t)NB * XW * 2);             // 64: Qb | ctxc | ffn1 | y1
  float* wbuf = (float*)take(4ull * NB * 8 * 4 * 4); //  8
  const size_t base_needed = off;                     // ~189 MiB

  // Tiered FFN batch buffer: [S][R][FH] bf16 for R rows per chunk.
  u16* ffnb = nullptr;
  long RCH = 0;
  if (base_needed + 4ull * NB * FH * 2 <= ws_size) {
    ffnb = (u16*)take(4ull * NB * FH * 2);  RCH = NB;        // +256 MiB
  } else if (base_needed + 2ull * NB * FH * 2 <= ws_size) {
    ffnb = (u16*)take(2ull * NB * FH * 2);  RCH = NB / 2;    // +128 MiB
  }

  u16* Qb   = (u16*)U1;   // [S][B][512]
  u16* ctxc = (u16*)U1;   // [B][2048]
  u16* ffn1 = (u16*)U1;   // [B][2048] per stream (sequential fallback)
  u16* y1   = (u16*)U1;   // [B][1024]
  float* attn0 = (float*)d_out + (size_t)NB * DM;

  if (base_needed > ws_size) return;  // diagnostic: clean fail instead of GPU fault

  // weight prep: fp32 -> bf16, transposed to [N][K] (coalesced LDS transpose)
  k_tcvt<<<dim3(16, 16, 8), dim3(256), 0, stream>>>(Wq, WqT, DM, DM);
  k_tcvt<<<dim3(16, 16, 8), dim3(256), 0, stream>>>(Wk, WkT, DM, DM);
  k_tcvt<<<dim3(16, 16, 8), dim3(256), 0, stream>>>(Wv, WvT, DM, DM);
  k_tcvt<<<dim3(16, 16, 8), dim3(256), 0, stream>>>(Wo, WoT, DM, DM);
  k_tcvt<<<dim3(64, 16, 8), dim3(256), 0, stream>>>(W1, W1T, DM, FH);
  k_tcvt<<<dim3(16, 64, 8), dim3(256), 0, stream>>>(W2, W2T, FH, DM);
  k_tcvt<<<dim3(32, 64, 1), dim3(256), 0, stream>>>(Wf1, Wf1T, XW, 1024);
  k_tcvt<<<dim3(16, 32, 1), dim3(256), 0, stream>>>(Wf2, Wf2T, 1024, DM);
  k_pack<<<dim3(2048), dim3(256), 0, stream>>>(t0, t1, t2, t3, xcat);

  const long WSQ = (long)DM * DM;
  for (int ly = 0; ly < 2; ++ly) {
    const u16* WqT_l = WqT + (size_t)ly * 4 * WSQ;
    const u16* WkT_l = WkT + (size_t)ly * 4 * WSQ;
    const u16* WvT_l = WvT + (size_t)ly * 4 * WSQ;
    const u16* WoT_l = WoT + (size_t)ly * 4 * WSQ;
    // Q projection, all streams in one launch (z = s)
    k_gemm<false, false, false><<<dim3(128, 4, 4), dim3(256), 0, stream>>>(
        xcat, XW, DM, WqT_l, WSQ, bq + (size_t)ly * XW, DM,
        nullptr, 0, 0, Qb, DM, (long)NB * DM, DM);
    // K projection + fused q.k dot: z = kp, N = 2048 (all 4 streams' Wk)
    k_kdot<<<dim3(128, 16, 4), dim3(256), 0, stream>>>(xcat, WkT_l, Qb, wbuf);
    k_softmax<<<dim3(4 * NB * 8 / 256), dim3(256), 0, stream>>>(
        wbuf, (ly == 0) ? attn0 : (float*)nullptr);
    // V projection via pre-mixed A (4x fewer FLOPs), one K=512 GEMM
    k_gemmvm<<<dim3(128, 16), dim3(256), 0, stream>>>(
        xcat, WvT_l, bv + (size_t)ly * XW, wbuf, ctxc);
    // O projection, residual-fused, in-place into xcat (z = s)
    k_gemm<false, true, false><<<dim3(128, 4, 4), dim3(256), 0, stream>>>(
        ctxc, XW, DM, WoT_l, WSQ, bo + (size_t)ly * XW, DM,
        xcat, XW, DM, xcat, XW, DM, DM);
    k_ln<<<dim3(NB), dim3(256), 0, stream>>>(xcat, lng + ly * XW, lnb + ly * XW);
    // FFN: z-batched over streams if workspace allows, else sequential
    if (RCH > 0) {
      for (long c0 = 0; c0 < NB; c0 += RCH) {
        k_gemm<true, false, false><<<dim3((int)(RCH / 128), 16, 4), dim3(256), 0, stream>>>(
            xcat + c0 * XW, XW, DM,
            W1T + (size_t)ly * 4 * DM * FH, (long)DM * FH,
            b1 + (size_t)ly * 4 * FH, FH,
            nullptr, 0, 0, ffnb, FH, (long)RCH * FH, DM);
        k_gemm<false, true, false><<<dim3((int)(RCH / 128), 4, 4), dim3(256), 0, stream>>>(
            ffnb, FH, (long)RCH * FH,
            W2T + (size_t)ly * 4 * FH * DM, (long)FH * DM,
            b2 + (size_t)ly * 4 * DM, DM,
            xcat + c0 * XW, XW, DM, xcat + c0 * XW, XW, DM, FH);
      }
    } else {
      for (int s = 0; s < NS; ++s) {
        const size_t wsl = (size_t)(ly * 4 + s);
        k_gemm<true, false, false><<<dim3(128, 16, 1), dim3(256), 0, stream>>>(
            xcat + s * DM, XW, 0, W1T + wsl * (size_t)DM * FH, 0, b1 + wsl * FH, 0,
            nullptr, 0, 0, ffn1, FH, 0, DM);
        k_gemm<false, true, false><<<dim3(128, 4, 1), dim3(256), 0, stream>>>(
            ffn1, FH, 0, W2T + wsl * (size_t)FH * DM, 0, b2 + wsl * DM, 0,
            xcat + s * DM, XW, 0, xcat + s * DM, XW, 0, FH);
      }
    }
  }
  // final fusion MLP
  k_gemm<true, false, false><<<dim3(128, 8, 1), dim3(256), 0, stream>>>(
      xcat, XW, 0, Wf1T, 0, bf1, 0, nullptr, 0, 0, y1, 1024, 0, XW);
  k_gemm<false, false, true><<<dim3(128, 4, 1), dim3(256), 0, stream>>>(
      y1, 1024, 0, Wf2T, 0, bf2, 0, nullptr, 0, 0, d_out, DM, 0, 1024);
}

// Round 13
// 2227.493 us; speedup vs baseline: 1.8306x; 1.0025x over previous
//
#include <hip/hip_runtime.h>
#include <stdint.h>

typedef unsigned short u16;
typedef __bf16 bf16x8 __attribute__((ext_vector_type(8)));
typedef float f32x4 __attribute__((ext_vector_type(4)));

constexpr int NB = 16384;        // batch tokens
constexpr int DM = 512;          // model dim
constexpr int NS = 4;            // streams
constexpr int FH = 2048;         // FFN hidden
constexpr int XW = NS * DM;      // 2048 concat width
constexpr float EPSL = 1e-5f;

__device__ __forceinline__ float bf2f(u16 u) { return __uint_as_float(((uint32_t)u) << 16); }
__device__ __forceinline__ u16 f2bf(float f) {
  uint32_t u = __float_as_uint(f);
  u += 0x7fffu + ((u >> 16) & 1u);
  return (u16)(u >> 16);
}
__device__ __forceinline__ void unpack8(uint4 p, float* f) {
  f[0] = __uint_as_float(p.x << 16); f[1] = __uint_as_float(p.x & 0xffff0000u);
  f[2] = __uint_as_float(p.y << 16); f[3] = __uint_as_float(p.y & 0xffff0000u);
  f[4] = __uint_as_float(p.z << 16); f[5] = __uint_as_float(p.z & 0xffff0000u);
  f[6] = __uint_as_float(p.w << 16); f[7] = __uint_as_float(p.w & 0xffff0000u);
}
__device__ __forceinline__ uint4 pack8(const float* f) {
  uint4 r;
  r.x = (uint32_t)f2bf(f[0]) | ((uint32_t)f2bf(f[1]) << 16);
  r.y = (uint32_t)f2bf(f[2]) | ((uint32_t)f2bf(f[3]) << 16);
  r.z = (uint32_t)f2bf(f[4]) | ((uint32_t)f2bf(f[5]) << 16);
  r.w = (uint32_t)f2bf(f[6]) | ((uint32_t)f2bf(f[7]) << 16);
  return r;
}
__device__ __forceinline__ uint32_t cvtpk(float lo, float hi) {
  uint32_t d;
  asm("v_cvt_pk_bf16_f32 %0, %1, %2" : "=v"(d) : "v"(lo), "v"(hi));
  return d;
}
__device__ __forceinline__ void gl_lds16(const void* g, void* l) {
  __builtin_amdgcn_global_load_lds((const __attribute__((address_space(1))) void*)g,
                                   (__attribute__((address_space(3))) void*)l, 16, 0, 0);
}

// XCD-aware bijective remap. gx%8==0 required (all launches satisfy).
__device__ __forceinline__ void remap(int& bx, int& by, int& bz) {
  const int gx = gridDim.x, gy = gridDim.y;
  const int fl = (blockIdx.z * gy + blockIdx.y) * gx + blockIdx.x;
  const int xcd = fl & 7;
  const int t = fl >> 3;
  const int bw = gx >> 3;
  bx = xcd * bw + t % bw;
  const int u = t / bw;
  by = u % gy;
  bz = u / gy;
}

// ---- counted-vmcnt 3-buffer GEMM core: 128x128 tile, BK=32, 256 threads ----
// (champion r5 core, byte-identical) LDS write-linear for global_load_lds;
// GLOBAL source 16B-block pre-permuted blk^=(row>>1)&3, reads apply the same
// XOR -> even bank spread (conflict-free). Pipeline: stage tile t+2 during
// compute of t; vmcnt(4) + raw s_barrier; loop body has no other vmem.
__device__ __forceinline__ void gemm_cv(
    const u16* __restrict__ A, int lda,
    const u16* __restrict__ Bt, int K,    // Bt row stride == K
    u16* As, u16* Bs, f32x4 (&acc)[4][4], int bx, int by)
{
  const int tid = threadIdx.x;
  const int ln = tid & 63;
  const int w  = tid >> 6;
  const int wm = w >> 1, wn = w & 1;
  const int m0 = bx * 128;
  const int n0 = by * 128;
  const int grow = ln >> 2;                                  // row within 16-chunk
  const int gcol = ((ln & 3) ^ ((ln >> 3) & 3)) * 8;         // swizzled src 16B-block
  const u16* Ab = A  + (size_t)(m0 + w * 32 + grow) * lda + gcol;
  const u16* Bb = Bt + (size_t)(n0 + w * 32 + grow) * K   + gcol;

  auto stage = [&](int buf, int k0) {
#pragma unroll
    for (int i = 0; i < 2; ++i) {
      gl_lds16(Ab + (size_t)i * 16 * lda + k0, &As[buf * 4096 + (w * 32 + i * 16) * 32]);
      gl_lds16(Bb + (size_t)i * 16 * K   + k0, &Bs[buf * 4096 + (w * 32 + i * 16) * 32]);
    }
  };

  __syncthreads();               // protect LDS reuse across successive calls
  const int nt = K >> 5;
  stage(0, 0);
  if (nt > 1) {
    stage(1, 32);
    asm volatile("s_waitcnt vmcnt(4)" ::: "memory");
  } else {
    asm volatile("s_waitcnt vmcnt(0)" ::: "memory");
  }
  __builtin_amdgcn_s_barrier();
  asm volatile("" ::: "memory");

  const int rx = ((ln & 15) >> 1) & 3;   // per-row read XOR
  const int qb = ln >> 4;
  const int cb = (qb ^ rx) * 8;          // swizzled read 16B-block (elems)
  int cur = 0, nxt2 = 2;
  for (int t = 0; t < nt; ++t) {
    bf16x8 af[4], bfv[4];
#pragma unroll
    for (int m = 0; m < 4; ++m) {
      af[m]  = *(const bf16x8*)&As[cur * 4096 + (wm * 64 + m * 16 + (ln & 15)) * 32 + cb];
      bfv[m] = *(const bf16x8*)&Bs[cur * 4096 + (wn * 64 + m * 16 + (ln & 15)) * 32 + cb];
    }
#pragma unroll
    for (int m = 0; m < 4; ++m)
#pragma unroll
      for (int n = 0; n < 4; ++n)
        acc[m][n] = __builtin_amdgcn_mfma_f32_16x16x32_bf16(af[m], bfv[n], acc[m][n], 0, 0, 0);
    if (t + 2 < nt) {
      stage(nxt2, (t + 2) * 32);
      asm volatile("s_waitcnt vmcnt(4)" ::: "memory");   // tile t+1 ready, t+2 in flight
      __builtin_amdgcn_s_barrier();
      asm volatile("" ::: "memory");
    } else if (t + 1 < nt) {
      asm volatile("s_waitcnt vmcnt(0)" ::: "memory");   // drain last tile
      __builtin_amdgcn_s_barrier();
      asm volatile("" ::: "memory");
    }
    cur = cur + 1;  if (cur == 3)  cur = 0;
    nxt2 = nxt2 + 1; if (nxt2 == 3) nxt2 = 0;
  }
  asm volatile("" ::: "memory");   // fence: epilogue vmem must not hoist into loop
}

// generic GEMM with per-z offsets: C = A*Bt^T + bias [+Rsd][ReLU]
template<bool RELU, bool RESID, bool OUTF32>
__global__ __launch_bounds__(256) void k_gemm(
    const u16* __restrict__ A, int lda, long aZ,
    const u16* __restrict__ Bt, long bZ,
    const float* __restrict__ bias, long biasZ,
    const u16* __restrict__ Rsd, int ldr, long rZ,
    void* __restrict__ Cp, int ldc, long cZ, int K)
{
  int bx, by, bz; remap(bx, by, bz);
  A += (long)bz * aZ; Bt += (long)bz * bZ; bias += (long)bz * biasZ;
  __shared__ alignas(16) u16 As[3 * 4096];
  __shared__ alignas(16) u16 Bs[3 * 4096];
  f32x4 acc[4][4] = {};
  gemm_cv(A, lda, Bt, K, As, Bs, acc, bx, by);
  const int ln = threadIdx.x & 63;
  const int w = threadIdx.x >> 6;
  const int wm = w >> 1, wn = w & 1;
  const int m0 = bx * 128, n0 = by * 128;
#pragma unroll
  for (int n = 0; n < 4; ++n) {
    const int gc = n0 + wn * 64 + n * 16 + (ln & 15);
    const float bv = bias[gc];
#pragma unroll
    for (int m = 0; m < 4; ++m) {
#pragma unroll
      for (int j = 0; j < 4; ++j) {
        const int gr = m0 + wm * 64 + m * 16 + (ln >> 4) * 4 + j;
        float v = acc[m][n][j] + bv;
        if constexpr (RESID) v += bf2f(Rsd[(long)bz * rZ + (size_t)gr * ldr + gc]);
        if constexpr (RELU)  v = v > 0.f ? v : 0.f;
        if constexpr (OUTF32) ((float*)Cp)[(long)bz * cZ + (size_t)gr * ldc + gc] = v;
        else                  ((u16*)Cp)[(long)bz * cZ + (size_t)gr * ldc + gc] = f2bf(v);
      }
    }
  }
}

// K-projection GEMM with fused q.k dot epilogue, N-BATCHED over streams:
// z = kp only; B = [2048][512] = all 4 streams' WkT (contiguous per layer).
// Writes raw scores (x1/8) to wbuf[s][b][h][kp]. K-bias softmax-invariant.
__global__ __launch_bounds__(256) void k_kdot(
    const u16* __restrict__ xcat, const u16* __restrict__ WkT_l,
    const u16* __restrict__ Qb, float* __restrict__ wbuf)
{
  int bx, by, kp; remap(bx, by, kp);
  __shared__ alignas(16) u16 As[3 * 4096];
  __shared__ alignas(16) u16 Bs[3 * 4096];
  f32x4 acc[4][4] = {};
  gemm_cv(xcat + kp * DM, XW, WkT_l, DM, As, Bs, acc, bx, by);
  const int ln = threadIdx.x & 63;
  const int w = threadIdx.x >> 6;
  const int wm = w >> 1, wn = w & 1;
  const int m0 = bx * 128, n0 = by * 128;
  const int colbase = n0 + wn * 64;
  const int s = colbase >> 9;
  const int h = (colbase >> 6) & 7;
  float p[4][4];
#pragma unroll
  for (int m = 0; m < 4; ++m)
#pragma unroll
    for (int j = 0; j < 4; ++j) p[m][j] = 0.f;
#pragma unroll
  for (int n = 0; n < 4; ++n) {
    const int qc = (colbase & 511) + n * 16 + (ln & 15);   // column within stream s
#pragma unroll
    for (int m = 0; m < 4; ++m) {
#pragma unroll
      for (int j = 0; j < 4; ++j) {
        const int gr = m0 + wm * 64 + m * 16 + (ln >> 4) * 4 + j;
        p[m][j] += acc[m][n][j] * bf2f(Qb[((size_t)s * NB + gr) * DM + qc]);
      }
    }
  }
#pragma unroll
  for (int m = 0; m < 4; ++m)
#pragma unroll
    for (int j = 0; j < 4; ++j) {
      float v = p[m][j];
      v += __shfl_xor(v, 1, 64);
      v += __shfl_xor(v, 2, 64);
      v += __shfl_xor(v, 4, 64);
      v += __shfl_xor(v, 8, 64);
      p[m][j] = v;
    }
  if ((ln & 15) == 0) {
#pragma unroll
    for (int m = 0; m < 4; ++m)
#pragma unroll
      for (int j = 0; j < 4; ++j) {
        const int gr = m0 + wm * 64 + m * 16 + (ln >> 4) * 4 + j;
        wbuf[(((size_t)s * NB + gr) * 8 + h) * 4 + kp] = p[m][j] * 0.125f;
      }
  }
}

// V-projection via PRE-MIXED A (FLOP cut 4x), DEPTH-2 reg-staged pipeline:
// ctx[b, s*512+c] = (sum_kp w[s,b,h(c),kp] x_kp[b,:]) . Wv[s][:,c] + bv.
// Tile k flows through reg-set (k&1), LDS buffers Am/Bsh[k&1].
// Iter t: issue loads for t+2 FIRST; MFMA(t); vmcnt(10) retires t+1's 10
// loads (issued one full iter ago -> ~500cy slack, covers L3); mix+ds_write
// t+1 into buffer protected by the barrier that ended iter t-1.
// Loop unrolled x2 so ALL register-array indices are compile-time (rule #20).
__global__ __launch_bounds__(256) void k_gemmvm(
    const u16* __restrict__ xcat, const u16* __restrict__ WvT_l,
    const float* __restrict__ bv_l, const float* __restrict__ wbuf,
    u16* __restrict__ ctxc)
{
  int bx, by, bz; remap(bx, by, bz); (void)bz;
  __shared__ alignas(16) u16 Am[2 * 8192];   // [buf][head j(2)][frag f(8)][512]
  __shared__ alignas(16) u16 Bsh[2 * 4096];  // [buf][frag f(8)][512]
  const int tid = threadIdx.x;
  const int ln = tid & 63;
  const int w  = tid >> 6;
  const int wm = w >> 1, wn = w & 1;
  const int m0 = bx * 128;
  const int n0 = by * 128;
  const int s  = n0 >> 9;
  const int h0 = (n0 >> 6) & 7;          // even head index of this block
  const int lr = ln & 15;
  const int kq = (ln >> 4) * 8;          // k sub-offset within 32-chunk
  const u16* Abase = xcat  + (size_t)(m0 + w * 32 + lr) * XW + kq;
  const u16* Bbase = WvT_l + (size_t)(n0 + w * 32 + lr) * DM + kq;

  // per-thread mix weights: rows r_i = m0 + (w*2+i)*16 + lr, heads h0+j
  float4 wg[2][2];
#pragma unroll
  for (int i = 0; i < 2; ++i) {
    const int r = m0 + (w * 2 + i) * 16 + lr;
#pragma unroll
    for (int j = 0; j < 2; ++j)
      wg[i][j] = *(const float4*)&wbuf[(((size_t)s * NB + r) * 8 + h0 + j) * 4];
  }

  // two NAMED register sets (compile-time indexed everywhere)
  uint4 arA0[2][4], arA1[2][4];   // [i][kp]
  uint4 brB0[2],    brB1[2];      // [i]

#define LOADT(AR, BR, k0)                                                     \
  {                                                                           \
    _Pragma("unroll")                                                         \
    for (int i = 0; i < 2; ++i) {                                             \
      _Pragma("unroll")                                                       \
      for (int kp = 0; kp < 4; ++kp)                                          \
        AR[i][kp] = *(const uint4*)(Abase + (size_t)i * 16 * XW + kp * DM + (k0)); \
      BR[i] = *(const uint4*)(Bbase + (size_t)i * 16 * DM + (k0));            \
    }                                                                         \
    asm volatile("" ::: "memory");                                            \
  }

#define MIXW(AR, BR, buf)                                                     \
  {                                                                           \
    _Pragma("unroll")                                                         \
    for (int i = 0; i < 2; ++i) {                                             \
      float x[4][8];                                                          \
      _Pragma("unroll")                                                       \
      for (int kp = 0; kp < 4; ++kp) unpack8(AR[i][kp], x[kp]);               \
      _Pragma("unroll")                                                       \
      for (int j = 0; j < 2; ++j) {                                           \
        const float4 g = wg[i][j];                                            \
        float o[8];                                                           \
        _Pragma("unroll")                                                     \
        for (int e = 0; e < 8; ++e)                                           \
          o[e] = g.x * x[0][e] + g.y * x[1][e] + g.z * x[2][e] + g.w * x[3][e]; \
        uint4 pk;                                                             \
        pk.x = cvtpk(o[0], o[1]); pk.y = cvtpk(o[2], o[3]);                   \
        pk.z = cvtpk(o[4], o[5]); pk.w = cvtpk(o[6], o[7]);                   \
        *(uint4*)&Am[(buf) * 8192 + ((j * 8) + (w * 2 + i)) * 512 + ln * 8] = pk; \
      }                                                                       \
      *(uint4*)&Bsh[(buf) * 4096 + (w * 2 + i) * 512 + ln * 8] = BR[i];       \
    }                                                                         \
  }

#define MFMAS(buf)                                                            \
  {                                                                           \
    bf16x8 af[4], bfv[4];                                                     \
    _Pragma("unroll")                                                         \
    for (int m = 0; m < 4; ++m)                                               \
      af[m] = *(const bf16x8*)&Am[(buf) * 8192 + (wn * 8 + wm * 4 + m) * 512 + ln * 8]; \
    _Pragma("unroll")                                                         \
    for (int n = 0; n < 4; ++n)                                               \
      bfv[n] = *(const bf16x8*)&Bsh[(buf) * 4096 + (wn * 4 + n) * 512 + ln * 8]; \
    _Pragma("unroll")                                                         \
    for (int m = 0; m < 4; ++m)                                               \
      _Pragma("unroll")                                                       \
      for (int n = 0; n < 4; ++n)                                             \
        acc[m][n] = __builtin_amdgcn_mfma_f32_16x16x32_bf16(af[m], bfv[n], acc[m][n], 0, 0, 0); \
  }

  f32x4 acc[4][4] = {};
  constexpr int nt = DM / 32;   // 16 (even)

  // prologue: tile0 -> set0 (mixed), tile1 -> set1 (in flight)
  LOADT(arA0, brB0, 0);
  asm volatile("s_waitcnt vmcnt(0)" ::: "memory");
  MIXW(arA0, brB0, 0);
  LOADT(arA1, brB1, 32);
  asm volatile("s_waitcnt lgkmcnt(0)" ::: "memory");
  __builtin_amdgcn_s_barrier();
  asm volatile("" ::: "memory");

#pragma unroll
  for (int t = 0; t < nt; t += 2) {
    // even iter t: compute buf0; prepare t+1 (set1) into buf1
    if (t + 2 < nt) LOADT(arA0, brB0, (t + 2) * 32);
    MFMAS(0);
    {
      if (t + 2 < nt) { asm volatile("s_waitcnt vmcnt(10)" ::: "memory"); }
      else            { asm volatile("s_waitcnt vmcnt(0)"  ::: "memory"); }
      MIXW(arA1, brB1, 1);
      asm volatile("s_waitcnt lgkmcnt(0)" ::: "memory");
      __builtin_amdgcn_s_barrier();
      asm volatile("" ::: "memory");
    }
    // odd iter t+1: compute buf1; prepare t+2 (set0) into buf0
    if (t + 3 < nt) LOADT(arA1, brB1, (t + 3) * 32);
    MFMAS(1);
    if (t + 2 < nt) {
      if (t + 3 < nt) { asm volatile("s_waitcnt vmcnt(10)" ::: "memory"); }
      else            { asm volatile("s_waitcnt vmcnt(0)"  ::: "memory"); }
      MIXW(arA0, brB0, 0);
      asm volatile("s_waitcnt lgkmcnt(0)" ::: "memory");
      __builtin_amdgcn_s_barrier();
      asm volatile("" ::: "memory");
    }
  }
#undef LOADT
#undef MIXW
#undef MFMAS

  // epilogue: + bias, bf16 store
#pragma unroll
  for (int nf = 0; nf < 4; ++nf) {
    const int gc = n0 + wn * 64 + nf * 16 + (ln & 15);
    const float bvv = bv_l[gc];
#pragma unroll
    for (int mf = 0; mf < 4; ++mf) {
#pragma unroll
      for (int j = 0; j < 4; ++j) {
        const int gr = m0 + wm * 64 + mf * 16 + (ln >> 4) * 4 + j;
        ctxc[(size_t)gr * XW + gc] = f2bf(acc[mf][nf][j] + bvv);
      }
    }
  }
}

// softmax over kp in-place on wbuf [S][B][H][4]; optional write to attn0
__global__ __launch_bounds__(256) void k_softmax(
    float* __restrict__ wbuf, float* __restrict__ a0)
{
  const int t = blockIdx.x * 256 + threadIdx.x;   // (s*NB + b)*8 + h
  float4 v = ((const float4*)wbuf)[t];
  const float mx = fmaxf(fmaxf(v.x, v.y), fmaxf(v.z, v.w));
  float4 e;
  e.x = __expf(v.x - mx); e.y = __expf(v.y - mx);
  e.z = __expf(v.z - mx); e.w = __expf(v.w - mx);
  const float inv = 1.f / (e.x + e.y + e.z + e.w);
  e.x *= inv; e.y *= inv; e.z *= inv; e.w *= inv;
  ((float4*)wbuf)[t] = e;
  if (a0 != nullptr) {
    const int s = t >> 17, b = (t >> 3) & (NB - 1), h = t & 7;
    ((float4*)a0)[((size_t)b * NS + s) * 8 + h] = e;
  }
}

// in-place LayerNorm over each 512-wide stream block of xcat; wave per (b,s)
__global__ __launch_bounds__(256) void k_ln(
    u16* __restrict__ xcat, const float* __restrict__ g, const float* __restrict__ bb)
{
  const int ln = threadIdx.x & 63;
  const int row = blockIdx.x * 4 + (threadIdx.x >> 6);
  const int b = row >> 2, s = row & 3;
  u16* p = xcat + (size_t)b * XW + s * DM;
  float v[8];
  { uint4 t = ((const uint4*)p)[ln]; unpack8(t, v); }
  float sum = 0.f;
#pragma unroll
  for (int j = 0; j < 8; ++j) sum += v[j];
#pragma unroll
  for (int off = 1; off < 64; off <<= 1) sum += __shfl_xor(sum, off, 64);
  const float mu = sum * (1.f / DM);
  float s2 = 0.f;
#pragma unroll
  for (int j = 0; j < 8; ++j) { float d = v[j] - mu; s2 += d * d; }
#pragma unroll
  for (int off = 1; off < 64; off <<= 1) s2 += __shfl_xor(s2, off, 64);
  const float rs = rsqrtf(s2 * (1.f / DM) + EPSL);
  const int e0 = s * DM + ln * 8;
  float o[8];
#pragma unroll
  for (int j = 0; j < 8; ++j) o[j] = (v[j] - mu) * rs * g[e0 + j] + bb[e0 + j];
  ((uint4*)p)[ln] = pack8(o);
}

// pack 4 fp32 streams -> xcat bf16 [B][S*D]
__global__ void k_pack(const float* __restrict__ t0, const float* __restrict__ t1,
                       const float* __restrict__ t2, const float* __restrict__ t3,
                       u16* __restrict__ xcat)
{
  const int total = NB * XW / 8;
  for (int t = blockIdx.x * blockDim.x + threadIdx.x; t < total; t += gridDim.x * blockDim.x) {
    const int b = t >> 8;
    const int r = t & 255;
    const int s = r >> 6;
    const int d0 = (r & 63) * 8;
    const float* p = (s == 0) ? t0 : (s == 1) ? t1 : (s == 2) ? t2 : t3;
    float f[8];
#pragma unroll
    for (int j = 0; j < 8; ++j) f[j] = p[(size_t)b * DM + d0 + j];
    ((uint4*)xcat)[t] = pack8(f);
  }
}

// coalesced transpose + fp32->bf16 via LDS 32x32 tiles.
__global__ __launch_bounds__(256) void k_tcvt(
    const float* __restrict__ src, u16* __restrict__ dst, int R, int C)
{
  __shared__ float tl[32][33];
  const int cx = blockIdx.x * 32, ry = blockIdx.y * 32;
  const size_t base = (size_t)blockIdx.z * R * C;
  const int lx = threadIdx.x & 31, ly = threadIdx.x >> 5;   // 8 rows per pass
#pragma unroll
  for (int i = 0; i < 32; i += 8)
    tl[ly + i][lx] = src[base + (size_t)(ry + ly + i) * C + cx + lx];
  __syncthreads();
#pragma unroll
  for (int i = 0; i < 32; i += 8)
    dst[base + (size_t)(cx + ly + i) * R + ry + lx] = f2bf(tl[lx][ly + i]);
}

extern "C" void kernel_launch(void* const* d_in, const int* in_sizes, int n_in,
                              void* d_out, int out_size, void* d_ws, size_t ws_size,
                              hipStream_t stream)
{
  (void)in_sizes; (void)n_in; (void)out_size;
  const float* t0  = (const float*)d_in[0];
  const float* t1  = (const float*)d_in[1];
  const float* t2  = (const float*)d_in[2];
  const float* t3  = (const float*)d_in[3];
  const float* Wq  = (const float*)d_in[4];
  const float* bq  = (const float*)d_in[5];
  const float* Wk  = (const float*)d_in[6];
  const float* Wv  = (const float*)d_in[8];
  const float* bv  = (const float*)d_in[9];
  const float* Wo  = (const float*)d_in[10];
  const float* bo  = (const float*)d_in[11];
  const float* lng = (const float*)d_in[12];
  const float* lnb = (const float*)d_in[13];
  const float* W1  = (const float*)d_in[14];
  const float* b1  = (const float*)d_in[15];
  const float* W2  = (const float*)d_in[16];
  const float* b2  = (const float*)d_in[17];
  const float* Wf1 = (const float*)d_in[18];
  const float* bf1 = (const float*)d_in[19];
  const float* Wf2 = (const float*)d_in[20];
  const float* bf2 = (const float*)d_in[21];

  size_t off = 0;
  char* ws = (char*)d_ws;
  auto take = [&](size_t n) { char* p = ws + off; off += (n + 255) & ~(size_t)255; return p; };
  u16* WqT  = (u16*)take(8ull * DM * DM * 2);        //  4 MiB
  u16* WkT  = (u16*)take(8ull * DM * DM * 2);        //  4
  u16* WvT  = (u16*)take(8ull * DM * DM * 2);        //  4
  u16* WoT  = (u16*)take(8ull * DM * DM * 2);        //  4
  u16* W1T  = (u16*)take(8ull * DM * FH * 2);        // 16
  u16* W2T  = (u16*)take(8ull * FH * DM * 2);        // 16
  u16* Wf1T = (u16*)take((size_t)XW * 1024 * 2);     //  4
  u16* Wf2T = (u16*)take((size_t)1024 * DM * 2);     //  1
  u16* xcat = (u16*)take((size_t)NB * XW * 2);       // 64
  char* U1  = take((size_t)NB * XW * 2);             // 64: Qb | ctxc | ffn1 | y1
  float* wbuf = (float*)take(4ull * NB * 8 * 4 * 4); //  8
  const size_t base_needed = off;                     // ~189 MiB

  // Tiered FFN batch buffer: [S][R][FH] bf16 for R rows per chunk.
  u16* ffnb = nullptr;
  long RCH = 0;
  if (base_needed + 4ull * NB * FH * 2 <= ws_size) {
    ffnb = (u16*)take(4ull * NB * FH * 2);  RCH = NB;        // +256 MiB
  } else if (base_needed + 2ull * NB * FH * 2 <= ws_size) {
    ffnb = (u16*)take(2ull * NB * FH * 2);  RCH = NB / 2;    // +128 MiB
  }

  u16* Qb   = (u16*)U1;   // [S][B][512]
  u16* ctxc = (u16*)U1;   // [B][2048]
  u16* ffn1 = (u16*)U1;   // [B][2048] per stream (sequential fallback)
  u16* y1   = (u16*)U1;   // [B][1024]
  float* attn0 = (float*)d_out + (size_t)NB * DM;

  if (base_needed > ws_size) return;  // diagnostic: clean fail instead of GPU fault

  // weight prep: fp32 -> bf16, transposed to [N][K] (coalesced LDS transpose)
  k_tcvt<<<dim3(16, 16, 8), dim3(256), 0, stream>>>(Wq, WqT, DM, DM);
  k_tcvt<<<dim3(16, 16, 8), dim3(256), 0, stream>>>(Wk, WkT, DM, DM);
  k_tcvt<<<dim3(16, 16, 8), dim3(256), 0, stream>>>(Wv, WvT, DM, DM);
  k_tcvt<<<dim3(16, 16, 8), dim3(256), 0, stream>>>(Wo, WoT, DM, DM);
  k_tcvt<<<dim3(64, 16, 8), dim3(256), 0, stream>>>(W1, W1T, DM, FH);
  k_tcvt<<<dim3(16, 64, 8), dim3(256), 0, stream>>>(W2, W2T, FH, DM);
  k_tcvt<<<dim3(32, 64, 1), dim3(256), 0, stream>>>(Wf1, Wf1T, XW, 1024);
  k_tcvt<<<dim3(16, 32, 1), dim3(256), 0, stream>>>(Wf2, Wf2T, 1024, DM);
  k_pack<<<dim3(2048), dim3(256), 0, stream>>>(t0, t1, t2, t3, xcat);

  const long WSQ = (long)DM * DM;
  for (int ly = 0; ly < 2; ++ly) {
    const u16* WqT_l = WqT + (size_t)ly * 4 * WSQ;
    const u16* WkT_l = WkT + (size_t)ly * 4 * WSQ;
    const u16* WvT_l = WvT + (size_t)ly * 4 * WSQ;
    const u16* WoT_l = WoT + (size_t)ly * 4 * WSQ;
    // Q projection, all streams in one launch (z = s)
    k_gemm<false, false, false><<<dim3(128, 4, 4), dim3(256), 0, stream>>>(
        xcat, XW, DM, WqT_l, WSQ, bq + (size_t)ly * XW, DM,
        nullptr, 0, 0, Qb, DM, (long)NB * DM, DM);
    // K projection + fused q.k dot: z = kp, N = 2048 (all 4 streams' Wk)
    k_kdot<<<dim3(128, 16, 4), dim3(256), 0, stream>>>(xcat, WkT_l, Qb, wbuf);
    k_softmax<<<dim3(4 * NB * 8 / 256), dim3(256), 0, stream>>>(
        wbuf, (ly == 0) ? attn0 : (float*)nullptr);
    // V projection via pre-mixed A (4x fewer FLOPs), depth-2 pipeline
    k_gemmvm<<<dim3(128, 16), dim3(256), 0, stream>>>(
        xcat, WvT_l, bv + (size_t)ly * XW, wbuf, ctxc);
    // O projection, residual-fused, in-place into xcat (z = s)
    k_gemm<false, true, false><<<dim3(128, 4, 4), dim3(256), 0, stream>>>(
        ctxc, XW, DM, WoT_l, WSQ, bo + (size_t)ly * XW, DM,
        xcat, XW, DM, xcat, XW, DM, DM);
    k_ln<<<dim3(NB), dim3(256), 0, stream>>>(xcat, lng + ly * XW, lnb + ly * XW);
    // FFN: z-batched over streams if workspace allows, else sequential
    if (RCH > 0) {
      for (long c0 = 0; c0 < NB; c0 += RCH) {
        k_gemm<true, false, false><<<dim3((int)(RCH / 128), 16, 4), dim3(256), 0, stream>>>(
            xcat + c0 * XW, XW, DM,
            W1T + (size_t)ly * 4 * DM * FH, (long)DM * FH,
            b1 + (size_t)ly * 4 * FH, FH,
            nullptr, 0, 0, ffnb, FH, (long)RCH * FH, DM);
        k_gemm<false, true, false><<<dim3((int)(RCH / 128), 4, 4), dim3(256), 0, stream>>>(
            ffnb, FH, (long)RCH * FH,
            W2T + (size_t)ly * 4 * FH * DM, (long)FH * DM,
            b2 + (size_t)ly * 4 * DM, DM,
            xcat + c0 * XW, XW, DM, xcat + c0 * XW, XW, DM, FH);
      }
    } else {
      for (int s = 0; s < NS; ++s) {
        const size_t wsl = (size_t)(ly * 4 + s);
        k_gemm<true, false, false><<<dim3(128, 16, 1), dim3(256), 0, stream>>>(
            xcat + s * DM, XW, 0, W1T + wsl * (size_t)DM * FH, 0, b1 + wsl * FH, 0,
            nullptr, 0, 0, ffn1, FH, 0, DM);
        k_gemm<false, true, false><<<dim3(128, 4, 1), dim3(256), 0, stream>>>(
            ffn1, FH, 0, W2T + wsl * (size_t)FH * DM, 0, b2 + wsl * DM, 0,
            xcat + s * DM, XW, 0, xcat + s * DM, XW, 0, FH);
      }
    }
  }
  // final fusion MLP
  k_gemm<true, false, false><<<dim3(128, 8, 1), dim3(256), 0, stream>>>(
      xcat, XW, 0, Wf1T, 0, bf1, 0, nullptr, 0, 0, y1, 1024, 0, XW);
  k_gemm<false, false, true><<<dim3(128, 4, 1), dim3(256), 0, stream>>>(
      y1, 1024, 0, Wf2T, 0, bf2, 0, nullptr, 0, 0, d_out, DM, 0, 1024);
}